// Round 8
// baseline (22005.412 us; speedup 1.0000x reference)
//
#include <hip/hip_runtime.h>
#include <hip/hip_bf16.h>
#include <cstdio>

typedef unsigned short ushort_t;
typedef unsigned long long u64;
typedef __attribute__((ext_vector_type(4))) float f32x4;
typedef __attribute__((ext_vector_type(4))) unsigned int u32x4;
typedef __attribute__((ext_vector_type(8))) __bf16 bf16x8;
typedef __attribute__((ext_vector_type(8))) unsigned short u16x8;
typedef __attribute__((ext_vector_type(4))) unsigned short u16x4;

#define B_  16
#define T_  1024
#define H_  512
#define NG  2048          // 4*H
#define M_  (B_*T_)       // 16384
#define NBLK_DIR 16       // lstm blocks per direction
#define FLG_STRIDE 64     // u32s per (dir) flag row (16 used, 256B padded)

__device__ inline unsigned short f2bf_rne(float f){
  union { float f; unsigned int u; } v; v.f = f;
  unsigned int u = v.u;
  unsigned int r = (u + 0x7fffu + ((u >> 16) & 1u)) >> 16;
  return (unsigned short)r;
}
__device__ inline float bf2f(unsigned short s){
  union { unsigned int u; float f; } v; v.u = ((unsigned int)s) << 16;
  return v.f;
}
__device__ inline float sigm_f(float x){
  return 1.0f / (1.0f + __expf(-x));
}
__device__ inline float tanh_f(float x){
  return 1.0f - 2.0f / (__expf(2.0f * x) + 1.0f);
}

__global__ void zero_u32(unsigned* __restrict__ p, int n){
  int i = blockIdx.x * blockDim.x + threadIdx.x;
  if (i < n) p[i] = 0u;
}

// ---------------- split f32 -> bf16 hi + bf16 lo ----------------
__global__ void split_f32_bf16(const float* __restrict__ src,
                               ushort_t* __restrict__ hi, ushort_t* __restrict__ lo,
                               int n4){
  int i = blockIdx.x * blockDim.x + threadIdx.x;
  int stride = gridDim.x * blockDim.x;
  for (; i < n4; i += stride){
    f32x4 v = ((const f32x4*)src)[i];
    u16x4 h4, l4;
    #pragma unroll
    for (int j = 0; j < 4; j++){
      unsigned short h = f2bf_rne(v[j]);
      h4[j] = h;
      l4[j] = f2bf_rne(v[j] - bf2f(h));
    }
    ((u16x4*)hi)[i] = h4;
    ((u16x4*)lo)[i] = l4;
  }
}

// ---------------- split-bf16 MFMA GEMM: C = A * B^T + bias ----------------
__global__ __launch_bounds__(256) void gemm_xg(
    const ushort_t* __restrict__ Ahi, const ushort_t* __restrict__ Alo,
    const ushort_t* __restrict__ Bhi0, const ushort_t* __restrict__ Blo0,
    const ushort_t* __restrict__ Bhi1, const ushort_t* __restrict__ Blo1,
    const float* __restrict__ bi0, const float* __restrict__ bh0,
    const float* __restrict__ bi1, const float* __restrict__ bh1,
    float* __restrict__ C0, float* __restrict__ C1,
    int M, int N, int K)
{
  __shared__ ushort_t As[128*32];
  __shared__ ushort_t Bs[128*32];
  const int tid  = threadIdx.x;
  const int wave = tid >> 6, lane = tid & 63;
  const int l15 = lane & 15, l4 = lane >> 4;
  const int wr = wave >> 1, wc = wave & 1;
  const int n0 = blockIdx.x * 128, m0 = blockIdx.y * 128;
  const int dir = blockIdx.z;
  const ushort_t* Bhi = dir ? Bhi1 : Bhi0;
  const ushort_t* Blo = dir ? Blo1 : Blo0;
  const float* bia = dir ? bi1 : bi0;
  const float* bib = dir ? bh1 : bh0;
  float* C = dir ? C1 : C0;

  f32x4 acc[4][4];
  #pragma unroll
  for (int i = 0; i < 4; i++)
    #pragma unroll
    for (int j = 0; j < 4; j++) acc[i][j] = (f32x4){0.f,0.f,0.f,0.f};

  const int e0 = tid, e1 = 256 + tid;
  const int row0 = e0 >> 2, c80 = (e0 & 3) * 8;
  const int row1 = e1 >> 2, c81 = (e1 & 3) * 8;

  for (int seg = 0; seg < 3; ++seg){
    const ushort_t* Ap = (seg == 2) ? Alo : Ahi;
    const ushort_t* Bp = (seg == 1) ? Blo : Bhi;
    for (int kt = 0; kt < K; kt += 32){
      __builtin_amdgcn_global_load_lds(
        (const __attribute__((address_space(1))) unsigned int*)(Ap + (size_t)(m0 + row0) * K + kt + c80),
        (__attribute__((address_space(3))) unsigned int*)(As + e0 * 8), 16, 0, 0);
      __builtin_amdgcn_global_load_lds(
        (const __attribute__((address_space(1))) unsigned int*)(Bp + (size_t)(n0 + row0) * K + kt + c80),
        (__attribute__((address_space(3))) unsigned int*)(Bs + e0 * 8), 16, 0, 0);
      __builtin_amdgcn_global_load_lds(
        (const __attribute__((address_space(1))) unsigned int*)(Ap + (size_t)(m0 + row1) * K + kt + c81),
        (__attribute__((address_space(3))) unsigned int*)(As + e1 * 8), 16, 0, 0);
      __builtin_amdgcn_global_load_lds(
        (const __attribute__((address_space(1))) unsigned int*)(Bp + (size_t)(n0 + row1) * K + kt + c81),
        (__attribute__((address_space(3))) unsigned int*)(Bs + e1 * 8), 16, 0, 0);
      __syncthreads();
      bf16x8 af[4], bfr[4];
      #pragma unroll
      for (int m = 0; m < 4; m++)
        af[m] = *(const bf16x8*)(As + (wr*64 + m*16 + l15) * 32 + l4 * 8);
      #pragma unroll
      for (int n = 0; n < 4; n++)
        bfr[n] = *(const bf16x8*)(Bs + (wc*64 + n*16 + l15) * 32 + l4 * 8);
      #pragma unroll
      for (int m = 0; m < 4; m++)
        #pragma unroll
        for (int n = 0; n < 4; n++)
          acc[m][n] = __builtin_amdgcn_mfma_f32_16x16x32_bf16(af[m], bfr[n], acc[m][n], 0, 0, 0);
      __syncthreads();
    }
  }
  #pragma unroll
  for (int m = 0; m < 4; m++)
    #pragma unroll
    for (int n = 0; n < 4; n++){
      int col = n0 + wc*64 + n*16 + l15;
      float bias = bia[col] + bib[col];
      #pragma unroll
      for (int r = 0; r < 4; r++){
        int row = m0 + wr*64 + m*16 + l4*4 + r;
        C[(size_t)row * N + col] = acc[m][n][r] + bias;
      }
    }
}

// ---------------- persistent bidirectional LSTM layer (fragment-ordered exchange) ----------------
// 32 blocks x 512 threads. Block = (dir = blk>>4, cb = blk&15), owns h-cols [32*cb,+32).
// hbuf GLOBAL layout = MFMA fragment order: u64 index g = tid*16 + 2i + e holds
// (batch=(tid>>2)&15, col=(i*8+(tid>>6))*8+(tid&3)*2+e), value (tag<<32)|(bf16hi|bf16lo<<16).
//  -> consumer thread tid sweeps 16 CONTIGUOUS u64 (128B; wave = 8KB coalesced)
//  -> unpack writes LDS words {i*512+tid}: conflict-free (bank = tid mod 32)
//  -> frag reads are r5's proven layout (no swizzle)
// Sync: SPECULATIVE sweep issued before the 16-lane flag poll (loads fly during poll);
// per-u64 tag validation + masked contiguous retry. Producer stores fire-and-forget.
__global__ __launch_bounds__(512, 1) void lstm_layer(
    const float* __restrict__ whh_fwd, const float* __restrict__ whh_bwd,
    const float* __restrict__ xg,      // [2][M_][NG], m = b*T + t
    u64* __restrict__ hbuf,            // [2 dir][2 parity][8192] u64 (fragment order)
    unsigned* __restrict__ flags,      // [2 dir][FLG_STRIDE] u32 (16 used)
    float* __restrict__ out_f32,       // [B][T][1024] or null
    ushort_t* __restrict__ out_hi,     // [B][T][1024] or null (split output)
    ushort_t* __restrict__ out_lo)
{
  const int dir = blockIdx.x >> 4;
  const int cb  = blockIdx.x & 15;
  const int tid = threadIdx.x;
  const int wave = tid >> 6, lane = tid & 63;
  const int gate = wave >> 1, ch = wave & 1;
  const int l15 = lane & 15, l4 = lane >> 4;
  const float* whh = dir ? whh_bwd : whh_fwd;
  u64* hb = hbuf + (size_t)dir * 2 * 8192;          // [parity][8192]
  unsigned* flg = flags + (size_t)dir * FLG_STRIDE; // 16 u32, one line

  __shared__ ushort_t hfhi[8192];   // fragment order: 16B unit u = colblk*16 + batch
  __shared__ ushort_t hflo[8192];
  __shared__ float gbuf[4][16][33];

  // --- W_hh fragments (split bf16): wave rows gate*512 + cb*32 + ch*16 + l15 ---
  bf16x8 Whi[16], Wlo[16];
  {
    const int wrow = gate * 512 + cb * 32 + ch * 16 + l15;
    const float* p0 = whh + (size_t)wrow * 512;
    #pragma unroll
    for (int s = 0; s < 16; s++){
      const float* p = p0 + s * 32 + l4 * 8;
      f32x4 va = *(const f32x4*)(p);
      f32x4 vb = *(const f32x4*)(p + 4);
      u16x8 th, tl;
      #pragma unroll
      for (int j = 0; j < 4; j++){
        unsigned short h = f2bf_rne(va[j]);
        th[j] = h; tl[j] = f2bf_rne(va[j] - bf2f(h));
        unsigned short h2 = f2bf_rne(vb[j]);
        th[4+j] = h2; tl[4+j] = f2bf_rne(vb[j] - bf2f(h2));
      }
      Whi[s] = __builtin_bit_cast(bf16x8, th);
      Wlo[s] = __builtin_bit_cast(bf16x8, tl);
    }
  }

  const int eb = tid >> 5, ecl = tid & 31, ecol = cb * 32 + ecl;

  // producer store slot (fragment-order g for this thread's (eb, ecol)):
  //   colblk = ecol>>3; g = (((colblk&7)<<6) + (eb<<2) + ((ecl>>1)&3))*16 + ((colblk>>3)<<1) + (ecl&1)
  const int p_colblk = ecol >> 3;
  const size_t g_store = (size_t)((((p_colblk & 7) << 6) + (eb << 2) + ((ecl >> 1) & 3)) * 16
                                  + ((p_colblk >> 3) << 1) + (ecl & 1));

  // --- init: publish own slice of h_0 (zeros, tag=1), then flag=1 (fire-and-forget) ---
  __hip_atomic_store(&hb[g_store], (u64)1u << 32, __ATOMIC_RELAXED, __HIP_MEMORY_SCOPE_AGENT);
  if (tid == 0)
    __hip_atomic_store(&flg[cb], 1u, __ATOMIC_RELAXED, __HIP_MEMORY_SCOPE_AGENT);

  float c_state = 0.0f;

  for (int t = 0; t < T_; ++t){
    // A) prefetch xg for this step (latency hides under poll/sweep)
    const int t_eff = dir ? (T_ - 1 - t) : t;
    const float* xgp = xg + ((size_t)dir * M_ + (size_t)eb * T_ + t_eff) * NG + ecol;
    float xi = xgp[0];
    float xf = xgp[512];
    float xgg = xgp[1024];
    float xo = xgp[1536];

    // B) SPECULATIVE sweep: issue 16 contiguous u64 loads (128B/thread) immediately
    const unsigned want = (unsigned)(t + 1);
    const u64* src = hb + (size_t)(t & 1) * 8192 + (size_t)tid * 16;
    u64 va[8], vb[8];
    #pragma unroll
    for (int i = 0; i < 8; i++){
      va[i] = __hip_atomic_load(&src[2 * i],     __ATOMIC_RELAXED, __HIP_MEMORY_SCOPE_AGENT);
      vb[i] = __hip_atomic_load(&src[2 * i + 1], __ATOMIC_RELAXED, __HIP_MEMORY_SCOPE_AGENT);
    }

    // C) slim poll: 16 lanes watch one 64B flag line (loads above stay in flight)
    if (tid < NBLK_DIR){
      while (__hip_atomic_load(&flg[tid], __ATOMIC_RELAXED, __HIP_MEMORY_SCOPE_AGENT) < want)
        __builtin_amdgcn_s_sleep(1);
    }
    __syncthreads();

    // D) validate tags; masked contiguous retry for stragglers
    for (;;){
      unsigned stale = 0;
      #pragma unroll
      for (int i = 0; i < 8; i++){
        if ((unsigned)(va[i] >> 32) != want || (unsigned)(vb[i] >> 32) != want)
          stale |= 1u << i;
      }
      if (!stale) break;
      #pragma unroll
      for (int i = 0; i < 8; i++){
        if (stale & (1u << i)){
          va[i] = __hip_atomic_load(&src[2 * i],     __ATOMIC_RELAXED, __HIP_MEMORY_SCOPE_AGENT);
          vb[i] = __hip_atomic_load(&src[2 * i + 1], __ATOMIC_RELAXED, __HIP_MEMORY_SCOPE_AGENT);
        }
      }
    }
    // unpack: LDS word i*512 + tid  (bank = tid mod 32 -> conflict-free)
    #pragma unroll
    for (int i = 0; i < 8; i++){
      unsigned d0 = (unsigned)va[i], d1 = (unsigned)vb[i];
      ((unsigned*)hfhi)[i * 512 + tid] = (d0 & 0xffffu) | (d1 << 16);
      ((unsigned*)hflo)[i * 512 + tid] = (d0 >> 16) | (d1 & 0xffff0000u);
    }
    __syncthreads();

    // E) gates: 3 independent MFMA chains (r5 fragment layout, no swizzle)
    {
      f32x4 a0 = {0.f,0.f,0.f,0.f}, a1 = a0, a2 = a0;
      #pragma unroll
      for (int s = 0; s < 16; s++){
        bf16x8 ah = *(const bf16x8*)&hfhi[(s * 64 + l4 * 16 + l15) * 8];
        bf16x8 al = *(const bf16x8*)&hflo[(s * 64 + l4 * 16 + l15) * 8];
        a0 = __builtin_amdgcn_mfma_f32_16x16x32_bf16(ah, Whi[s], a0, 0, 0, 0);
        a1 = __builtin_amdgcn_mfma_f32_16x16x32_bf16(ah, Wlo[s], a1, 0, 0, 0);
        a2 = __builtin_amdgcn_mfma_f32_16x16x32_bf16(al, Whi[s], a2, 0, 0, 0);
      }
      f32x4 acc = a0 + a1;
      acc = acc + a2;
      #pragma unroll
      for (int r = 0; r < 4; r++)
        gbuf[gate][l4 * 4 + r][ch * 16 + l15] = acc[r];
    }
    __syncthreads();

    // F) cell + publish: tagged data store then flag store, all fire-and-forget
    {
      float pi = gbuf[0][eb][ecl] + xi;
      float pf = gbuf[1][eb][ecl] + xf;
      float pg = gbuf[2][eb][ecl] + xgg;
      float po = gbuf[3][eb][ecl] + xo;
      float ig = sigm_f(pi);
      float fg = sigm_f(pf);
      float gg = tanh_f(pg);
      float og = sigm_f(po);
      c_state = fg * c_state + ig * gg;
      float h = og * tanh_f(c_state);
      unsigned short hh = f2bf_rne(h);
      unsigned short hl = f2bf_rne(h - bf2f(hh));
      unsigned pack = (unsigned)hh | ((unsigned)hl << 16);
      u64 v = ((u64)(unsigned)(t + 2) << 32) | (u64)pack;
      __hip_atomic_store(&hb[(size_t)((t + 1) & 1) * 8192 + g_store], v,
                         __ATOMIC_RELAXED, __HIP_MEMORY_SCOPE_AGENT);
      if (tid == 0)
        __hip_atomic_store(&flg[cb], (unsigned)(t + 2), __ATOMIC_RELAXED, __HIP_MEMORY_SCOPE_AGENT);
      // output stores (off critical path)
      size_t oidx = ((size_t)eb * T_ + t_eff) * 1024 + dir * 512 + ecol;
      if (out_f32) out_f32[oidx] = h;
      if (out_hi){ out_hi[oidx] = hh; out_lo[oidx] = hl; }
    }
  }
}

// ---------------- attention pooling ----------------
__device__ inline float dot4(f32x4 a, f32x4 b){
  return a[0]*b[0] + a[1]*b[1] + a[2]*b[2] + a[3]*b[3];
}

__global__ __launch_bounds__(256) void attn_pool(
    const float* __restrict__ out1,   // [B][T][1024]
    const float* __restrict__ aw,     // [1024]
    const float* __restrict__ ab,     // [1]
    float* __restrict__ enc)          // [B][1024]
{
  __shared__ float wbuf[1024];
  __shared__ float sc[1024];
  __shared__ float red[16];
  const int b = blockIdx.x;
  const int tid = threadIdx.x;
  const int wave = tid >> 6, lane = tid & 63;
  ((f32x4*)wbuf)[tid] = ((const f32x4*)aw)[tid];
  __syncthreads();
  const float* ob = out1 + (size_t)b * T_ * 1024;
  const float bias = ab[0];

  for (int t = wave; t < T_; t += 4){
    const float* row = ob + (size_t)t * 1024;
    float s = dot4(((const f32x4*)row)[lane],       ((const f32x4*)wbuf)[lane])
            + dot4(((const f32x4*)row)[lane + 64],  ((const f32x4*)wbuf)[lane + 64])
            + dot4(((const f32x4*)row)[lane + 128], ((const f32x4*)wbuf)[lane + 128])
            + dot4(((const f32x4*)row)[lane + 192], ((const f32x4*)wbuf)[lane + 192]);
    #pragma unroll
    for (int o = 32; o > 0; o >>= 1) s += __shfl_xor(s, o, 64);
    if (lane == 0) sc[t] = s + bias;
  }
  __syncthreads();

  float m = -1e30f;
  for (int i = tid; i < 1024; i += 256) m = fmaxf(m, sc[i]);
  #pragma unroll
  for (int o = 32; o > 0; o >>= 1) m = fmaxf(m, __shfl_xor(m, o, 64));
  if (lane == 0) red[wave] = m;
  __syncthreads();
  m = fmaxf(fmaxf(red[0], red[1]), fmaxf(red[2], red[3]));

  float ssum = 0.f;
  for (int i = tid; i < 1024; i += 256){
    float p = __expf(sc[i] - m);
    sc[i] = p;
    ssum += p;
  }
  #pragma unroll
  for (int o = 32; o > 0; o >>= 1) ssum += __shfl_xor(ssum, o, 64);
  if (lane == 0) red[8 + wave] = ssum;
  __syncthreads();
  float inv = 1.0f / (red[8] + red[9] + red[10] + red[11]);

  f32x4 a = {0.f,0.f,0.f,0.f};
  for (int t = 0; t < T_; t++){
    f32x4 v = *(const f32x4*)(ob + (size_t)t * 1024 + tid * 4);
    float p = sc[t];
    a[0] += p * v[0]; a[1] += p * v[1]; a[2] += p * v[2]; a[3] += p * v[3];
  }
  f32x4 r = { a[0]*inv, a[1]*inv, a[2]*inv, a[3]*inv };
  *(f32x4*)(enc + (size_t)b * 1024 + tid * 4) = r;
}

// ---------------- host ----------------
extern "C" void kernel_launch(void* const* d_in, const int* in_sizes, int n_in,
                              void* d_out, int out_size, void* d_ws, size_t ws_size,
                              hipStream_t stream)
{
  const float* x        = (const float*)d_in[0];
  const float* w_ih_l0  = (const float*)d_in[1];
  const float* w_hh_l0  = (const float*)d_in[2];
  const float* b_ih_l0  = (const float*)d_in[3];
  const float* b_hh_l0  = (const float*)d_in[4];
  const float* w_ih_l0r = (const float*)d_in[5];
  const float* w_hh_l0r = (const float*)d_in[6];
  const float* b_ih_l0r = (const float*)d_in[7];
  const float* b_hh_l0r = (const float*)d_in[8];
  const float* w_ih_l1  = (const float*)d_in[9];
  const float* w_hh_l1  = (const float*)d_in[10];
  const float* b_ih_l1  = (const float*)d_in[11];
  const float* b_hh_l1  = (const float*)d_in[12];
  const float* w_ih_l1r = (const float*)d_in[13];
  const float* w_hh_l1r = (const float*)d_in[14];
  const float* b_ih_l1r = (const float*)d_in[15];
  const float* b_hh_l1r = (const float*)d_in[16];
  const float* attn_w   = (const float*)d_in[17];
  const float* attn_b   = (const float*)d_in[18];
  float* enc = (float*)d_out;

  char* ws = (char*)d_ws;
  size_t off = 0;
  auto alloc = [&](size_t bytes) -> void* {
    void* p = ws + off;
    off += (bytes + 255) & ~(size_t)255;
    return p;
  };
  ushort_t* Ahi  = (ushort_t*)alloc((size_t)M_ * 2048 * 2);
  ushort_t* Alo  = (ushort_t*)alloc((size_t)M_ * 2048 * 2);
  ushort_t* Whi0 = (ushort_t*)alloc((size_t)2048 * 2048 * 2);
  ushort_t* Wlo0 = (ushort_t*)alloc((size_t)2048 * 2048 * 2);
  ushort_t* Whi1 = (ushort_t*)alloc((size_t)2048 * 2048 * 2);
  ushort_t* Wlo1 = (ushort_t*)alloc((size_t)2048 * 2048 * 2);
  float*    xg   = (float*)alloc((size_t)2 * M_ * NG * 4);
  float*    outb = (float*)alloc((size_t)M_ * 1024 * 4);
  u64*      hbuf = (u64*)alloc((size_t)2 * 2 * 2 * 8192 * 8);   // [layer][dir][parity][8192]
  unsigned* flags= (unsigned*)alloc((size_t)2 * 2 * FLG_STRIDE * 4); // [layer][dir][..]
  if (off > ws_size){
    fprintf(stderr, "kernel_launch: workspace too small: need %zu have %zu\n", off, ws_size);
    return;
  }

  // zero tagged h buffers + flags every call (replay-deterministic)
  {
    int n = (int)((size_t)2 * 2 * 2 * 8192 * 8 / 4) + 2 * 2 * FLG_STRIDE;
    zero_u32<<<(n + 255) / 256, 256, 0, stream>>>((unsigned*)hbuf, n);
  }

  // ---- layer 0 ----
  split_f32_bf16<<<2048, 256, 0, stream>>>(x, Ahi, Alo, M_ * 2048 / 4);
  split_f32_bf16<<<512, 256, 0, stream>>>(w_ih_l0,  Whi0, Wlo0, 2048 * 2048 / 4);
  split_f32_bf16<<<512, 256, 0, stream>>>(w_ih_l0r, Whi1, Wlo1, 2048 * 2048 / 4);
  gemm_xg<<<dim3(16, 128, 2), 256, 0, stream>>>(
      Ahi, Alo, Whi0, Wlo0, Whi1, Wlo1,
      b_ih_l0, b_hh_l0, b_ih_l0r, b_hh_l0r,
      xg, xg + (size_t)M_ * NG, M_, NG, 2048);
  lstm_layer<<<32, 512, 0, stream>>>(w_hh_l0, w_hh_l0r, xg, hbuf, flags,
                                     nullptr, Ahi, Alo);
  // ---- layer 1 ----
  split_f32_bf16<<<512, 256, 0, stream>>>(w_ih_l1,  Whi0, Wlo0, 2048 * 1024 / 4);
  split_f32_bf16<<<512, 256, 0, stream>>>(w_ih_l1r, Whi1, Wlo1, 2048 * 1024 / 4);
  gemm_xg<<<dim3(16, 128, 2), 256, 0, stream>>>(
      Ahi, Alo, Whi0, Wlo0, Whi1, Wlo1,
      b_ih_l1, b_hh_l1, b_ih_l1r, b_hh_l1r,
      xg, xg + (size_t)M_ * NG, M_, NG, 1024);
  lstm_layer<<<32, 512, 0, stream>>>(w_hh_l1, w_hh_l1r, xg,
                                     hbuf + (size_t)2 * 2 * 8192,
                                     flags + (size_t)2 * FLG_STRIDE,
                                     outb, nullptr, nullptr);
  // ---- attention pooling ----
  attn_pool<<<16, 256, 0, stream>>>(outb, attn_w, attn_b, enc);
}

// Round 9
// 16759.363 us; speedup vs baseline: 1.3130x; 1.3130x over previous
//
#include <hip/hip_runtime.h>
#include <hip/hip_bf16.h>
#include <cstdio>

typedef unsigned short ushort_t;
typedef unsigned long long u64;
typedef __attribute__((ext_vector_type(4))) float f32x4;
typedef __attribute__((ext_vector_type(4))) unsigned int u32x4;
typedef __attribute__((ext_vector_type(8))) __bf16 bf16x8;
typedef __attribute__((ext_vector_type(8))) unsigned short u16x8;
typedef __attribute__((ext_vector_type(4))) unsigned short u16x4;

#define B_  16
#define T_  1024
#define H_  512
#define NG  2048          // 4*H
#define M_  (B_*T_)       // 16384
#define NBLK_DIR 16       // lstm blocks per direction
#define FLG_STRIDE 64     // u32s per (dir) flag row (16 used, 256B padded)

__device__ inline unsigned short f2bf_rne(float f){
  union { float f; unsigned int u; } v; v.f = f;
  unsigned int u = v.u;
  unsigned int r = (u + 0x7fffu + ((u >> 16) & 1u)) >> 16;
  return (unsigned short)r;
}
__device__ inline float bf2f(unsigned short s){
  union { unsigned int u; float f; } v; v.u = ((unsigned int)s) << 16;
  return v.f;
}
__device__ inline float sigm_f(float x){
  return 1.0f / (1.0f + __expf(-x));
}
__device__ inline float tanh_f(float x){
  return 1.0f - 2.0f / (__expf(2.0f * x) + 1.0f);
}

__global__ void zero_u32(unsigned* __restrict__ p, int n){
  int i = blockIdx.x * blockDim.x + threadIdx.x;
  if (i < n) p[i] = 0u;
}

// ---------------- split f32 -> bf16 hi + bf16 lo ----------------
__global__ void split_f32_bf16(const float* __restrict__ src,
                               ushort_t* __restrict__ hi, ushort_t* __restrict__ lo,
                               int n4){
  int i = blockIdx.x * blockDim.x + threadIdx.x;
  int stride = gridDim.x * blockDim.x;
  for (; i < n4; i += stride){
    f32x4 v = ((const f32x4*)src)[i];
    u16x4 h4, l4;
    #pragma unroll
    for (int j = 0; j < 4; j++){
      unsigned short h = f2bf_rne(v[j]);
      h4[j] = h;
      l4[j] = f2bf_rne(v[j] - bf2f(h));
    }
    ((u16x4*)hi)[i] = h4;
    ((u16x4*)lo)[i] = l4;
  }
}

// ---------------- split-bf16 MFMA GEMM: C = A * B^T + bias ----------------
__global__ __launch_bounds__(256) void gemm_xg(
    const ushort_t* __restrict__ Ahi, const ushort_t* __restrict__ Alo,
    const ushort_t* __restrict__ Bhi0, const ushort_t* __restrict__ Blo0,
    const ushort_t* __restrict__ Bhi1, const ushort_t* __restrict__ Blo1,
    const float* __restrict__ bi0, const float* __restrict__ bh0,
    const float* __restrict__ bi1, const float* __restrict__ bh1,
    float* __restrict__ C0, float* __restrict__ C1,
    int M, int N, int K)
{
  __shared__ ushort_t As[128*32];
  __shared__ ushort_t Bs[128*32];
  const int tid  = threadIdx.x;
  const int wave = tid >> 6, lane = tid & 63;
  const int l15 = lane & 15, l4 = lane >> 4;
  const int wr = wave >> 1, wc = wave & 1;
  const int n0 = blockIdx.x * 128, m0 = blockIdx.y * 128;
  const int dir = blockIdx.z;
  const ushort_t* Bhi = dir ? Bhi1 : Bhi0;
  const ushort_t* Blo = dir ? Blo1 : Blo0;
  const float* bia = dir ? bi1 : bi0;
  const float* bib = dir ? bh1 : bh0;
  float* C = dir ? C1 : C0;

  f32x4 acc[4][4];
  #pragma unroll
  for (int i = 0; i < 4; i++)
    #pragma unroll
    for (int j = 0; j < 4; j++) acc[i][j] = (f32x4){0.f,0.f,0.f,0.f};

  const int e0 = tid, e1 = 256 + tid;
  const int row0 = e0 >> 2, c80 = (e0 & 3) * 8;
  const int row1 = e1 >> 2, c81 = (e1 & 3) * 8;

  for (int seg = 0; seg < 3; ++seg){
    const ushort_t* Ap = (seg == 2) ? Alo : Ahi;
    const ushort_t* Bp = (seg == 1) ? Blo : Bhi;
    for (int kt = 0; kt < K; kt += 32){
      __builtin_amdgcn_global_load_lds(
        (const __attribute__((address_space(1))) unsigned int*)(Ap + (size_t)(m0 + row0) * K + kt + c80),
        (__attribute__((address_space(3))) unsigned int*)(As + e0 * 8), 16, 0, 0);
      __builtin_amdgcn_global_load_lds(
        (const __attribute__((address_space(1))) unsigned int*)(Bp + (size_t)(n0 + row0) * K + kt + c80),
        (__attribute__((address_space(3))) unsigned int*)(Bs + e0 * 8), 16, 0, 0);
      __builtin_amdgcn_global_load_lds(
        (const __attribute__((address_space(1))) unsigned int*)(Ap + (size_t)(m0 + row1) * K + kt + c81),
        (__attribute__((address_space(3))) unsigned int*)(As + e1 * 8), 16, 0, 0);
      __builtin_amdgcn_global_load_lds(
        (const __attribute__((address_space(1))) unsigned int*)(Bp + (size_t)(n0 + row1) * K + kt + c81),
        (__attribute__((address_space(3))) unsigned int*)(Bs + e1 * 8), 16, 0, 0);
      __syncthreads();
      bf16x8 af[4], bfr[4];
      #pragma unroll
      for (int m = 0; m < 4; m++)
        af[m] = *(const bf16x8*)(As + (wr*64 + m*16 + l15) * 32 + l4 * 8);
      #pragma unroll
      for (int n = 0; n < 4; n++)
        bfr[n] = *(const bf16x8*)(Bs + (wc*64 + n*16 + l15) * 32 + l4 * 8);
      #pragma unroll
      for (int m = 0; m < 4; m++)
        #pragma unroll
        for (int n = 0; n < 4; n++)
          acc[m][n] = __builtin_amdgcn_mfma_f32_16x16x32_bf16(af[m], bfr[n], acc[m][n], 0, 0, 0);
      __syncthreads();
    }
  }
  #pragma unroll
  for (int m = 0; m < 4; m++)
    #pragma unroll
    for (int n = 0; n < 4; n++){
      int col = n0 + wc*64 + n*16 + l15;
      float bias = bia[col] + bib[col];
      #pragma unroll
      for (int r = 0; r < 4; r++){
        int row = m0 + wr*64 + m*16 + l4*4 + r;
        C[(size_t)row * N + col] = acc[m][n][r] + bias;
      }
    }
}

// ---------------- persistent bidirectional LSTM layer (fragment-ordered exchange) ----------------
// 32 blocks x 512 threads. Block = (dir = blk>>4, cb = blk&15), owns h-cols [32*cb,+32).
// hbuf GLOBAL layout = MFMA fragment order: u64 index g = tid*16 + 2i + e holds
// (batch=(tid>>2)&15, col=(i*8+(tid>>6))*8+(tid&3)*2+e), value (tag<<32)|(bf16hi|bf16lo<<16).
//  -> consumer thread tid sweeps 16 CONTIGUOUS u64 (128B; wave = 8KB coalesced)
//  -> unpack writes LDS words {i*512+tid}: conflict-free (bank = tid mod 32)
//  -> frag reads are r5's proven layout (no swizzle)
// Sync: slim 16-lane flag poll FIRST, then ONE bulk sweep (r7 discipline — the r8
// speculative pre-poll sweep always read stale and doubled traffic), per-u64 tag
// validation + masked contiguous retry. Producer stores fire-and-forget.
__global__ __launch_bounds__(512, 1) void lstm_layer(
    const float* __restrict__ whh_fwd, const float* __restrict__ whh_bwd,
    const float* __restrict__ xg,      // [2][M_][NG], m = b*T + t
    u64* __restrict__ hbuf,            // [2 dir][2 parity][8192] u64 (fragment order)
    unsigned* __restrict__ flags,      // [2 dir][FLG_STRIDE] u32 (16 used)
    float* __restrict__ out_f32,       // [B][T][1024] or null
    ushort_t* __restrict__ out_hi,     // [B][T][1024] or null (split output)
    ushort_t* __restrict__ out_lo)
{
  const int dir = blockIdx.x >> 4;
  const int cb  = blockIdx.x & 15;
  const int tid = threadIdx.x;
  const int wave = tid >> 6, lane = tid & 63;
  const int gate = wave >> 1, ch = wave & 1;
  const int l15 = lane & 15, l4 = lane >> 4;
  const float* whh = dir ? whh_bwd : whh_fwd;
  u64* hb = hbuf + (size_t)dir * 2 * 8192;          // [parity][8192]
  unsigned* flg = flags + (size_t)dir * FLG_STRIDE; // 16 u32, one line

  __shared__ ushort_t hfhi[8192];   // fragment order: 16B unit u = colblk*16 + batch
  __shared__ ushort_t hflo[8192];
  __shared__ float gbuf[4][16][33];

  // --- W_hh fragments (split bf16): wave rows gate*512 + cb*32 + ch*16 + l15 ---
  bf16x8 Whi[16], Wlo[16];
  {
    const int wrow = gate * 512 + cb * 32 + ch * 16 + l15;
    const float* p0 = whh + (size_t)wrow * 512;
    #pragma unroll
    for (int s = 0; s < 16; s++){
      const float* p = p0 + s * 32 + l4 * 8;
      f32x4 va = *(const f32x4*)(p);
      f32x4 vb = *(const f32x4*)(p + 4);
      u16x8 th, tl;
      #pragma unroll
      for (int j = 0; j < 4; j++){
        unsigned short h = f2bf_rne(va[j]);
        th[j] = h; tl[j] = f2bf_rne(va[j] - bf2f(h));
        unsigned short h2 = f2bf_rne(vb[j]);
        th[4+j] = h2; tl[4+j] = f2bf_rne(vb[j] - bf2f(h2));
      }
      Whi[s] = __builtin_bit_cast(bf16x8, th);
      Wlo[s] = __builtin_bit_cast(bf16x8, tl);
    }
  }

  const int eb = tid >> 5, ecl = tid & 31, ecol = cb * 32 + ecl;

  // producer store slot (fragment-order g for this thread's (eb, ecol)):
  //   colblk = ecol>>3; g = (((colblk&7)<<6) + (eb<<2) + ((ecl>>1)&3))*16 + ((colblk>>3)<<1) + (ecl&1)
  const int p_colblk = ecol >> 3;
  const size_t g_store = (size_t)((((p_colblk & 7) << 6) + (eb << 2) + ((ecl >> 1) & 3)) * 16
                                  + ((p_colblk >> 3) << 1) + (ecl & 1));

  // --- init: publish own slice of h_0 (zeros, tag=1), then flag=1 (fire-and-forget) ---
  __hip_atomic_store(&hb[g_store], (u64)1u << 32, __ATOMIC_RELAXED, __HIP_MEMORY_SCOPE_AGENT);
  if (tid == 0)
    __hip_atomic_store(&flg[cb], 1u, __ATOMIC_RELAXED, __HIP_MEMORY_SCOPE_AGENT);

  float c_state = 0.0f;

  for (int t = 0; t < T_; ++t){
    // A) prefetch xg for this step (latency hides under the poll)
    const int t_eff = dir ? (T_ - 1 - t) : t;
    const float* xgp = xg + ((size_t)dir * M_ + (size_t)eb * T_ + t_eff) * NG + ecol;
    float xi = xgp[0];
    float xf = xgp[512];
    float xgg = xgp[1024];
    float xo = xgp[1536];

    // B) slim poll: 16 lanes watch one 64B flag line (monotone values)
    const unsigned want = (unsigned)(t + 1);
    if (tid < NBLK_DIR){
      while (__hip_atomic_load(&flg[tid], __ATOMIC_RELAXED, __HIP_MEMORY_SCOPE_AGENT) < want)
        __builtin_amdgcn_s_sleep(1);
    }
    __syncthreads();

    // C) ONE bulk sweep AFTER the poll: 16 contiguous u64 (128B/thread, coalesced)
    const u64* src = hb + (size_t)(t & 1) * 8192 + (size_t)tid * 16;
    u64 va[8], vb[8];
    #pragma unroll
    for (int i = 0; i < 8; i++){
      va[i] = __hip_atomic_load(&src[2 * i],     __ATOMIC_RELAXED, __HIP_MEMORY_SCOPE_AGENT);
      vb[i] = __hip_atomic_load(&src[2 * i + 1], __ATOMIC_RELAXED, __HIP_MEMORY_SCOPE_AGENT);
    }
    // D) validate tags; masked contiguous retry for flag-beats-data stragglers
    for (;;){
      unsigned stale = 0;
      #pragma unroll
      for (int i = 0; i < 8; i++){
        if ((unsigned)(va[i] >> 32) != want || (unsigned)(vb[i] >> 32) != want)
          stale |= 1u << i;
      }
      if (!stale) break;
      #pragma unroll
      for (int i = 0; i < 8; i++){
        if (stale & (1u << i)){
          va[i] = __hip_atomic_load(&src[2 * i],     __ATOMIC_RELAXED, __HIP_MEMORY_SCOPE_AGENT);
          vb[i] = __hip_atomic_load(&src[2 * i + 1], __ATOMIC_RELAXED, __HIP_MEMORY_SCOPE_AGENT);
        }
      }
    }
    // unpack: LDS word i*512 + tid  (bank = tid mod 32 -> conflict-free)
    #pragma unroll
    for (int i = 0; i < 8; i++){
      unsigned d0 = (unsigned)va[i], d1 = (unsigned)vb[i];
      ((unsigned*)hfhi)[i * 512 + tid] = (d0 & 0xffffu) | (d1 << 16);
      ((unsigned*)hflo)[i * 512 + tid] = (d0 >> 16) | (d1 & 0xffff0000u);
    }
    __syncthreads();

    // E) gates: 3 independent MFMA chains (r5 fragment layout, no swizzle)
    {
      f32x4 a0 = {0.f,0.f,0.f,0.f}, a1 = a0, a2 = a0;
      #pragma unroll
      for (int s = 0; s < 16; s++){
        bf16x8 ah = *(const bf16x8*)&hfhi[(s * 64 + l4 * 16 + l15) * 8];
        bf16x8 al = *(const bf16x8*)&hflo[(s * 64 + l4 * 16 + l15) * 8];
        a0 = __builtin_amdgcn_mfma_f32_16x16x32_bf16(ah, Whi[s], a0, 0, 0, 0);
        a1 = __builtin_amdgcn_mfma_f32_16x16x32_bf16(ah, Wlo[s], a1, 0, 0, 0);
        a2 = __builtin_amdgcn_mfma_f32_16x16x32_bf16(al, Whi[s], a2, 0, 0, 0);
      }
      f32x4 acc = a0 + a1;
      acc = acc + a2;
      #pragma unroll
      for (int r = 0; r < 4; r++)
        gbuf[gate][l4 * 4 + r][ch * 16 + l15] = acc[r];
    }
    __syncthreads();

    // F) cell + publish: tagged data store then flag store, all fire-and-forget
    {
      float pi = gbuf[0][eb][ecl] + xi;
      float pf = gbuf[1][eb][ecl] + xf;
      float pg = gbuf[2][eb][ecl] + xgg;
      float po = gbuf[3][eb][ecl] + xo;
      float ig = sigm_f(pi);
      float fg = sigm_f(pf);
      float gg = tanh_f(pg);
      float og = sigm_f(po);
      c_state = fg * c_state + ig * gg;
      float h = og * tanh_f(c_state);
      unsigned short hh = f2bf_rne(h);
      unsigned short hl = f2bf_rne(h - bf2f(hh));
      unsigned pack = (unsigned)hh | ((unsigned)hl << 16);
      u64 v = ((u64)(unsigned)(t + 2) << 32) | (u64)pack;
      __hip_atomic_store(&hb[(size_t)((t + 1) & 1) * 8192 + g_store], v,
                         __ATOMIC_RELAXED, __HIP_MEMORY_SCOPE_AGENT);
      if (tid == 0)
        __hip_atomic_store(&flg[cb], (unsigned)(t + 2), __ATOMIC_RELAXED, __HIP_MEMORY_SCOPE_AGENT);
      // output stores (off critical path)
      size_t oidx = ((size_t)eb * T_ + t_eff) * 1024 + dir * 512 + ecol;
      if (out_f32) out_f32[oidx] = h;
      if (out_hi){ out_hi[oidx] = hh; out_lo[oidx] = hl; }
    }
  }
}

// ---------------- attention pooling ----------------
__device__ inline float dot4(f32x4 a, f32x4 b){
  return a[0]*b[0] + a[1]*b[1] + a[2]*b[2] + a[3]*b[3];
}

__global__ __launch_bounds__(256) void attn_pool(
    const float* __restrict__ out1,   // [B][T][1024]
    const float* __restrict__ aw,     // [1024]
    const float* __restrict__ ab,     // [1]
    float* __restrict__ enc)          // [B][1024]
{
  __shared__ float wbuf[1024];
  __shared__ float sc[1024];
  __shared__ float red[16];
  const int b = blockIdx.x;
  const int tid = threadIdx.x;
  const int wave = tid >> 6, lane = tid & 63;
  ((f32x4*)wbuf)[tid] = ((const f32x4*)aw)[tid];
  __syncthreads();
  const float* ob = out1 + (size_t)b * T_ * 1024;
  const float bias = ab[0];

  for (int t = wave; t < T_; t += 4){
    const float* row = ob + (size_t)t * 1024;
    float s = dot4(((const f32x4*)row)[lane],       ((const f32x4*)wbuf)[lane])
            + dot4(((const f32x4*)row)[lane + 64],  ((const f32x4*)wbuf)[lane + 64])
            + dot4(((const f32x4*)row)[lane + 128], ((const f32x4*)wbuf)[lane + 128])
            + dot4(((const f32x4*)row)[lane + 192], ((const f32x4*)wbuf)[lane + 192]);
    #pragma unroll
    for (int o = 32; o > 0; o >>= 1) s += __shfl_xor(s, o, 64);
    if (lane == 0) sc[t] = s + bias;
  }
  __syncthreads();

  float m = -1e30f;
  for (int i = tid; i < 1024; i += 256) m = fmaxf(m, sc[i]);
  #pragma unroll
  for (int o = 32; o > 0; o >>= 1) m = fmaxf(m, __shfl_xor(m, o, 64));
  if (lane == 0) red[wave] = m;
  __syncthreads();
  m = fmaxf(fmaxf(red[0], red[1]), fmaxf(red[2], red[3]));

  float ssum = 0.f;
  for (int i = tid; i < 1024; i += 256){
    float p = __expf(sc[i] - m);
    sc[i] = p;
    ssum += p;
  }
  #pragma unroll
  for (int o = 32; o > 0; o >>= 1) ssum += __shfl_xor(ssum, o, 64);
  if (lane == 0) red[8 + wave] = ssum;
  __syncthreads();
  float inv = 1.0f / (red[8] + red[9] + red[10] + red[11]);

  f32x4 a = {0.f,0.f,0.f,0.f};
  for (int t = 0; t < T_; t++){
    f32x4 v = *(const f32x4*)(ob + (size_t)t * 1024 + tid * 4);
    float p = sc[t];
    a[0] += p * v[0]; a[1] += p * v[1]; a[2] += p * v[2]; a[3] += p * v[3];
  }
  f32x4 r = { a[0]*inv, a[1]*inv, a[2]*inv, a[3]*inv };
  *(f32x4*)(enc + (size_t)b * 1024 + tid * 4) = r;
}

// ---------------- host ----------------
extern "C" void kernel_launch(void* const* d_in, const int* in_sizes, int n_in,
                              void* d_out, int out_size, void* d_ws, size_t ws_size,
                              hipStream_t stream)
{
  const float* x        = (const float*)d_in[0];
  const float* w_ih_l0  = (const float*)d_in[1];
  const float* w_hh_l0  = (const float*)d_in[2];
  const float* b_ih_l0  = (const float*)d_in[3];
  const float* b_hh_l0  = (const float*)d_in[4];
  const float* w_ih_l0r = (const float*)d_in[5];
  const float* w_hh_l0r = (const float*)d_in[6];
  const float* b_ih_l0r = (const float*)d_in[7];
  const float* b_hh_l0r = (const float*)d_in[8];
  const float* w_ih_l1  = (const float*)d_in[9];
  const float* w_hh_l1  = (const float*)d_in[10];
  const float* b_ih_l1  = (const float*)d_in[11];
  const float* b_hh_l1  = (const float*)d_in[12];
  const float* w_ih_l1r = (const float*)d_in[13];
  const float* w_hh_l1r = (const float*)d_in[14];
  const float* b_ih_l1r = (const float*)d_in[15];
  const float* b_hh_l1r = (const float*)d_in[16];
  const float* attn_w   = (const float*)d_in[17];
  const float* attn_b   = (const float*)d_in[18];
  float* enc = (float*)d_out;

  char* ws = (char*)d_ws;
  size_t off = 0;
  auto alloc = [&](size_t bytes) -> void* {
    void* p = ws + off;
    off += (bytes + 255) & ~(size_t)255;
    return p;
  };
  ushort_t* Ahi  = (ushort_t*)alloc((size_t)M_ * 2048 * 2);
  ushort_t* Alo  = (ushort_t*)alloc((size_t)M_ * 2048 * 2);
  ushort_t* Whi0 = (ushort_t*)alloc((size_t)2048 * 2048 * 2);
  ushort_t* Wlo0 = (ushort_t*)alloc((size_t)2048 * 2048 * 2);
  ushort_t* Whi1 = (ushort_t*)alloc((size_t)2048 * 2048 * 2);
  ushort_t* Wlo1 = (ushort_t*)alloc((size_t)2048 * 2048 * 2);
  float*    xg   = (float*)alloc((size_t)2 * M_ * NG * 4);
  float*    outb = (float*)alloc((size_t)M_ * 1024 * 4);
  u64*      hbuf = (u64*)alloc((size_t)2 * 2 * 2 * 8192 * 8);   // [layer][dir][parity][8192]
  unsigned* flags= (unsigned*)alloc((size_t)2 * 2 * FLG_STRIDE * 4); // [layer][dir][..]
  if (off > ws_size){
    fprintf(stderr, "kernel_launch: workspace too small: need %zu have %zu\n", off, ws_size);
    return;
  }

  // zero tagged h buffers + flags every call (replay-deterministic)
  {
    int n = (int)((size_t)2 * 2 * 2 * 8192 * 8 / 4) + 2 * 2 * FLG_STRIDE;
    zero_u32<<<(n + 255) / 256, 256, 0, stream>>>((unsigned*)hbuf, n);
  }

  // ---- layer 0 ----
  split_f32_bf16<<<2048, 256, 0, stream>>>(x, Ahi, Alo, M_ * 2048 / 4);
  split_f32_bf16<<<512, 256, 0, stream>>>(w_ih_l0,  Whi0, Wlo0, 2048 * 2048 / 4);
  split_f32_bf16<<<512, 256, 0, stream>>>(w_ih_l0r, Whi1, Wlo1, 2048 * 2048 / 4);
  gemm_xg<<<dim3(16, 128, 2), 256, 0, stream>>>(
      Ahi, Alo, Whi0, Wlo0, Whi1, Wlo1,
      b_ih_l0, b_hh_l0, b_ih_l0r, b_hh_l0r,
      xg, xg + (size_t)M_ * NG, M_, NG, 2048);
  lstm_layer<<<32, 512, 0, stream>>>(w_hh_l0, w_hh_l0r, xg, hbuf, flags,
                                     nullptr, Ahi, Alo);
  // ---- layer 1 ----
  split_f32_bf16<<<512, 256, 0, stream>>>(w_ih_l1,  Whi0, Wlo0, 2048 * 1024 / 4);
  split_f32_bf16<<<512, 256, 0, stream>>>(w_ih_l1r, Whi1, Wlo1, 2048 * 1024 / 4);
  gemm_xg<<<dim3(16, 128, 2), 256, 0, stream>>>(
      Ahi, Alo, Whi0, Wlo0, Whi1, Wlo1,
      b_ih_l1, b_hh_l1, b_ih_l1r, b_hh_l1r,
      xg, xg + (size_t)M_ * NG, M_, NG, 1024);
  lstm_layer<<<32, 512, 0, stream>>>(w_hh_l1, w_hh_l1r, xg,
                                     hbuf + (size_t)2 * 2 * 8192,
                                     flags + (size_t)2 * FLG_STRIDE,
                                     outb, nullptr, nullptr);
  // ---- attention pooling ----
  attn_pool<<<16, 256, 0, stream>>>(outb, attn_w, attn_b, enc);
}

// Round 10
// 12272.781 us; speedup vs baseline: 1.7930x; 1.3656x over previous
//
#include <hip/hip_runtime.h>
#include <hip/hip_bf16.h>
#include <cstdio>

typedef unsigned short ushort_t;
typedef unsigned long long u64;
typedef __attribute__((ext_vector_type(4))) float f32x4;
typedef __attribute__((ext_vector_type(4))) unsigned int u32x4;
typedef __attribute__((ext_vector_type(8))) __bf16 bf16x8;
typedef __attribute__((ext_vector_type(8))) unsigned short u16x8;
typedef __attribute__((ext_vector_type(4))) unsigned short u16x4;

#define B_  16
#define T_  1024
#define H_  512
#define NG  2048          // 4*H
#define M_  (B_*T_)       // 16384
#define NBLK_DIR 16       // lstm blocks per direction
#define FLG_LINE 16       // u32s per producer flag line (64B)

__device__ inline unsigned short f2bf_rne(float f){
  union { float f; unsigned int u; } v; v.f = f;
  unsigned int u = v.u;
  unsigned int r = (u + 0x7fffu + ((u >> 16) & 1u)) >> 16;
  return (unsigned short)r;
}
__device__ inline float bf2f(unsigned short s){
  union { unsigned int u; float f; } v; v.u = ((unsigned int)s) << 16;
  return v.f;
}
__device__ inline float sigm_f(float x){
  return 1.0f / (1.0f + __expf(-x));
}
__device__ inline float tanh_f(float x){
  return 1.0f - 2.0f / (__expf(2.0f * x) + 1.0f);
}

__global__ void zero_u32(unsigned* __restrict__ p, int n){
  int i = blockIdx.x * blockDim.x + threadIdx.x;
  if (i < n) p[i] = 0u;
}

// ---------------- split f32 -> bf16 hi + bf16 lo ----------------
__global__ void split_f32_bf16(const float* __restrict__ src,
                               ushort_t* __restrict__ hi, ushort_t* __restrict__ lo,
                               int n4){
  int i = blockIdx.x * blockDim.x + threadIdx.x;
  int stride = gridDim.x * blockDim.x;
  for (; i < n4; i += stride){
    f32x4 v = ((const f32x4*)src)[i];
    u16x4 h4, l4;
    #pragma unroll
    for (int j = 0; j < 4; j++){
      unsigned short h = f2bf_rne(v[j]);
      h4[j] = h;
      l4[j] = f2bf_rne(v[j] - bf2f(h));
    }
    ((u16x4*)hi)[i] = h4;
    ((u16x4*)lo)[i] = l4;
  }
}

// ---------------- split-bf16 MFMA GEMM: C = A * B^T + bias ----------------
__global__ __launch_bounds__(256) void gemm_xg(
    const ushort_t* __restrict__ Ahi, const ushort_t* __restrict__ Alo,
    const ushort_t* __restrict__ Bhi0, const ushort_t* __restrict__ Blo0,
    const ushort_t* __restrict__ Bhi1, const ushort_t* __restrict__ Blo1,
    const float* __restrict__ bi0, const float* __restrict__ bh0,
    const float* __restrict__ bi1, const float* __restrict__ bh1,
    float* __restrict__ C0, float* __restrict__ C1,
    int M, int N, int K)
{
  __shared__ ushort_t As[128*32];
  __shared__ ushort_t Bs[128*32];
  const int tid  = threadIdx.x;
  const int wave = tid >> 6, lane = tid & 63;
  const int l15 = lane & 15, l4 = lane >> 4;
  const int wr = wave >> 1, wc = wave & 1;
  const int n0 = blockIdx.x * 128, m0 = blockIdx.y * 128;
  const int dir = blockIdx.z;
  const ushort_t* Bhi = dir ? Bhi1 : Bhi0;
  const ushort_t* Blo = dir ? Blo1 : Blo0;
  const float* bia = dir ? bi1 : bi0;
  const float* bib = dir ? bh1 : bh0;
  float* C = dir ? C1 : C0;

  f32x4 acc[4][4];
  #pragma unroll
  for (int i = 0; i < 4; i++)
    #pragma unroll
    for (int j = 0; j < 4; j++) acc[i][j] = (f32x4){0.f,0.f,0.f,0.f};

  const int e0 = tid, e1 = 256 + tid;
  const int row0 = e0 >> 2, c80 = (e0 & 3) * 8;
  const int row1 = e1 >> 2, c81 = (e1 & 3) * 8;

  for (int seg = 0; seg < 3; ++seg){
    const ushort_t* Ap = (seg == 2) ? Alo : Ahi;
    const ushort_t* Bp = (seg == 1) ? Blo : Bhi;
    for (int kt = 0; kt < K; kt += 32){
      __builtin_amdgcn_global_load_lds(
        (const __attribute__((address_space(1))) unsigned int*)(Ap + (size_t)(m0 + row0) * K + kt + c80),
        (__attribute__((address_space(3))) unsigned int*)(As + e0 * 8), 16, 0, 0);
      __builtin_amdgcn_global_load_lds(
        (const __attribute__((address_space(1))) unsigned int*)(Bp + (size_t)(n0 + row0) * K + kt + c80),
        (__attribute__((address_space(3))) unsigned int*)(Bs + e0 * 8), 16, 0, 0);
      __builtin_amdgcn_global_load_lds(
        (const __attribute__((address_space(1))) unsigned int*)(Ap + (size_t)(m0 + row1) * K + kt + c81),
        (__attribute__((address_space(3))) unsigned int*)(As + e1 * 8), 16, 0, 0);
      __builtin_amdgcn_global_load_lds(
        (const __attribute__((address_space(1))) unsigned int*)(Bp + (size_t)(n0 + row1) * K + kt + c81),
        (__attribute__((address_space(3))) unsigned int*)(Bs + e1 * 8), 16, 0, 0);
      __syncthreads();
      bf16x8 af[4], bfr[4];
      #pragma unroll
      for (int m = 0; m < 4; m++)
        af[m] = *(const bf16x8*)(As + (wr*64 + m*16 + l15) * 32 + l4 * 8);
      #pragma unroll
      for (int n = 0; n < 4; n++)
        bfr[n] = *(const bf16x8*)(Bs + (wc*64 + n*16 + l15) * 32 + l4 * 8);
      #pragma unroll
      for (int m = 0; m < 4; m++)
        #pragma unroll
        for (int n = 0; n < 4; n++)
          acc[m][n] = __builtin_amdgcn_mfma_f32_16x16x32_bf16(af[m], bfr[n], acc[m][n], 0, 0, 0);
      __syncthreads();
    }
  }
  #pragma unroll
  for (int m = 0; m < 4; m++)
    #pragma unroll
    for (int n = 0; n < 4; n++){
      int col = n0 + wc*64 + n*16 + l15;
      float bias = bia[col] + bib[col];
      #pragma unroll
      for (int r = 0; r < 4; r++){
        int row = m0 + wr*64 + m*16 + l4*4 + r;
        C[(size_t)row * N + col] = acc[m][n][r] + bias;
      }
    }
}

// ---------------- persistent bidirectional LSTM layer ----------------
// 32 blocks x 512 threads. Block = (dir = blk>>4, cb = blk&15), owns h-cols [32*cb,+32).
// hbuf: chunk-major [dir][parity][producer_cb][512] u64 = (tag<<32)|(bf16hi|bf16lo<<16),
// idx in chunk = batch*32 + col_within. Producer stores contiguous (chunk + tid).
// PUBLISH (per wave): data store -> s_waitcnt vmcnt(0) (own stores LLC-visible) ->
// lane0 atomicAdd(+1) on the block's OWN flag line. Consumer polls 16 flag lines for
// count >= 8*(t+1): a satisfied poll implies data visible -> sweep reads fresh, the
// tag-retry loop is a never-firing safety net (FETCH_SIZE is the diagnostic).
// LDS: fragment unit u = colblk*16 + (b ^ (colblk&15)) -> unpack writes 2 lanes/bank
// (free) and ds_read_b128 reads a permuted contiguous block (clean).
__global__ __launch_bounds__(512, 1) void lstm_layer(
    const float* __restrict__ whh_fwd, const float* __restrict__ whh_bwd,
    const float* __restrict__ xg,      // [2][M_][NG], m = b*T + t
    u64* __restrict__ hbuf,            // [2 dir][2 parity][16][512] u64
    unsigned* __restrict__ flags,      // [2 dir][16 blk][FLG_LINE] u32
    float* __restrict__ out_f32,       // [B][T][1024] or null
    ushort_t* __restrict__ out_hi,     // [B][T][1024] or null (split output)
    ushort_t* __restrict__ out_lo)
{
  const int dir = blockIdx.x >> 4;
  const int cb  = blockIdx.x & 15;
  const int tid = threadIdx.x;
  const int wave = tid >> 6, lane = tid & 63;
  const int gate = wave >> 1, ch = wave & 1;
  const int l15 = lane & 15, l4 = lane >> 4;
  const float* whh = dir ? whh_bwd : whh_fwd;
  u64* hb = hbuf + (size_t)dir * 2 * 8192;                    // [parity][16][512]
  unsigned* flg = flags + (size_t)dir * NBLK_DIR * FLG_LINE;  // 16 lines

  __shared__ ushort_t hfhi[8192];   // 1024 x 16B units, u = colblk*16 + (b ^ (colblk&15))
  __shared__ ushort_t hflo[8192];
  __shared__ float gbuf[4][16][33];

  // --- W_hh fragments (split bf16): wave rows gate*512 + cb*32 + ch*16 + l15 ---
  bf16x8 Whi[16], Wlo[16];
  {
    const int wrow = gate * 512 + cb * 32 + ch * 16 + l15;
    const float* p0 = whh + (size_t)wrow * 512;
    #pragma unroll
    for (int s = 0; s < 16; s++){
      const float* p = p0 + s * 32 + l4 * 8;
      f32x4 va = *(const f32x4*)(p);
      f32x4 vb = *(const f32x4*)(p + 4);
      u16x8 th, tl;
      #pragma unroll
      for (int j = 0; j < 4; j++){
        unsigned short h = f2bf_rne(va[j]);
        th[j] = h; tl[j] = f2bf_rne(va[j] - bf2f(h));
        unsigned short h2 = f2bf_rne(vb[j]);
        th[4+j] = h2; tl[4+j] = f2bf_rne(vb[j] - bf2f(h2));
      }
      Whi[s] = __builtin_bit_cast(bf16x8, th);
      Wlo[s] = __builtin_bit_cast(bf16x8, tl);
    }
  }

  const int eb = tid >> 5, ecl = tid & 31, ecol = cb * 32 + ecl;

  // consumer sweep addressing: thread covers chunk p, col-pair (2a,2a+1), rows rh*8..+7
  const int p  = tid >> 5;
  const int a  = tid & 15;
  const int rh = (tid >> 4) & 1;
  const int colblk = p * 4 + (a >> 2);      // 16B-unit column block (0..63)
  const int jp = a & 3;                      // u32 slot within 16B unit
  const size_t cbase = (size_t)p * 512 + rh * 256 + 2 * a;

  // --- init: publish own slice of h_0 (zeros, tag=1); per-wave vmcnt ack then +1 ---
  __hip_atomic_store(&hb[cb * 512 + tid], (u64)1u << 32, __ATOMIC_RELAXED, __HIP_MEMORY_SCOPE_AGENT);
  asm volatile("s_waitcnt vmcnt(0)" ::: "memory");
  if (lane == 0)
    __hip_atomic_fetch_add(&flg[cb * FLG_LINE], 1u, __ATOMIC_RELAXED, __HIP_MEMORY_SCOPE_AGENT);

  float c_state = 0.0f;

  for (int t = 0; t < T_; ++t){
    // A) prefetch xg for this step (latency hides under the poll)
    const int t_eff = dir ? (T_ - 1 - t) : t;
    const float* xgp = xg + ((size_t)dir * M_ + (size_t)eb * T_ + t_eff) * NG + ecol;
    float xi = xgp[0];
    float xf = xgp[512];
    float xgg = xgp[1024];
    float xo = xgp[1536];

    // B) poll: 16 lanes watch 16 per-producer flag lines (count >= 8*(t+1))
    const unsigned want = (unsigned)(t + 1);
    const unsigned target = 8u * (unsigned)(t + 1);
    if (tid < NBLK_DIR){
      while (__hip_atomic_load(&flg[tid * FLG_LINE], __ATOMIC_RELAXED, __HIP_MEMORY_SCOPE_AGENT) < target)
        __builtin_amdgcn_s_sleep(1);
    }
    __syncthreads();

    // C) ONE bulk sweep (flag implies data visible): 16 u64s, 16B granules in one chunk
    const u64* src = hb + (size_t)(t & 1) * 8192 + cbase;
    u64 va[8], vb[8];
    #pragma unroll
    for (int i = 0; i < 8; i++){
      va[i] = __hip_atomic_load(&src[i * 32],     __ATOMIC_RELAXED, __HIP_MEMORY_SCOPE_AGENT);
      vb[i] = __hip_atomic_load(&src[i * 32 + 1], __ATOMIC_RELAXED, __HIP_MEMORY_SCOPE_AGENT);
    }
    // D) tag validation: safety net only (should never fire under the vmcnt protocol)
    for (;;){
      unsigned stale = 0;
      #pragma unroll
      for (int i = 0; i < 8; i++){
        if ((unsigned)(va[i] >> 32) != want || (unsigned)(vb[i] >> 32) != want)
          stale |= 1u << i;
      }
      if (!stale) break;
      #pragma unroll
      for (int i = 0; i < 8; i++){
        if (stale & (1u << i)){
          va[i] = __hip_atomic_load(&src[i * 32],     __ATOMIC_RELAXED, __HIP_MEMORY_SCOPE_AGENT);
          vb[i] = __hip_atomic_load(&src[i * 32 + 1], __ATOMIC_RELAXED, __HIP_MEMORY_SCOPE_AGENT);
        }
      }
    }
    // unpack into swizzled fragment LDS: u = colblk*16 + (b ^ (colblk&15))
    #pragma unroll
    for (int i = 0; i < 8; i++){
      unsigned d0 = (unsigned)va[i], d1 = (unsigned)vb[i];
      unsigned hi = (d0 & 0xffffu) | (d1 << 16);
      unsigned lo = (d0 >> 16) | (d1 & 0xffff0000u);
      int b = rh * 8 + i;
      int u = colblk * 16 + (b ^ (colblk & 15));
      ((unsigned*)hfhi)[u * 4 + jp] = hi;
      ((unsigned*)hflo)[u * 4 + jp] = lo;
    }
    __syncthreads();

    // E) gates: 3 independent MFMA chains; reads via the same unit swizzle
    {
      f32x4 a0 = {0.f,0.f,0.f,0.f}, a1 = a0, a2 = a0;
      #pragma unroll
      for (int s = 0; s < 16; s++){
        int qu = s * 4 + l4;
        int un = qu * 16 + (l15 ^ (qu & 15));
        bf16x8 ah = *(const bf16x8*)&hfhi[un * 8];
        bf16x8 al = *(const bf16x8*)&hflo[un * 8];
        a0 = __builtin_amdgcn_mfma_f32_16x16x32_bf16(ah, Whi[s], a0, 0, 0, 0);
        a1 = __builtin_amdgcn_mfma_f32_16x16x32_bf16(ah, Wlo[s], a1, 0, 0, 0);
        a2 = __builtin_amdgcn_mfma_f32_16x16x32_bf16(al, Whi[s], a2, 0, 0, 0);
      }
      f32x4 acc = a0 + a1;
      acc = acc + a2;
      #pragma unroll
      for (int r = 0; r < 4; r++)
        gbuf[gate][l4 * 4 + r][ch * 16 + l15] = acc[r];
    }
    __syncthreads();

    // F) cell + publish: data store -> per-wave vmcnt ack -> +1; out stores after
    {
      float pi = gbuf[0][eb][ecl] + xi;
      float pf = gbuf[1][eb][ecl] + xf;
      float pg = gbuf[2][eb][ecl] + xgg;
      float po = gbuf[3][eb][ecl] + xo;
      float ig = sigm_f(pi);
      float fg = sigm_f(pf);
      float gg = tanh_f(pg);
      float og = sigm_f(po);
      c_state = fg * c_state + ig * gg;
      float h = og * tanh_f(c_state);
      unsigned short hh = f2bf_rne(h);
      unsigned short hl = f2bf_rne(h - bf2f(hh));
      unsigned pack = (unsigned)hh | ((unsigned)hl << 16);
      u64 v = ((u64)(unsigned)(t + 2) << 32) | (u64)pack;
      __hip_atomic_store(&hb[(size_t)((t + 1) & 1) * 8192 + cb * 512 + tid], v,
                         __ATOMIC_RELAXED, __HIP_MEMORY_SCOPE_AGENT);
      asm volatile("s_waitcnt vmcnt(0)" ::: "memory");
      if (lane == 0)
        __hip_atomic_fetch_add(&flg[cb * FLG_LINE], 1u, __ATOMIC_RELAXED, __HIP_MEMORY_SCOPE_AGENT);
      // output stores (off critical path, after publish)
      size_t oidx = ((size_t)eb * T_ + t_eff) * 1024 + dir * 512 + ecol;
      if (out_f32) out_f32[oidx] = h;
      if (out_hi){ out_hi[oidx] = hh; out_lo[oidx] = hl; }
    }
  }
}

// ---------------- attention pooling ----------------
__device__ inline float dot4(f32x4 a, f32x4 b){
  return a[0]*b[0] + a[1]*b[1] + a[2]*b[2] + a[3]*b[3];
}

__global__ __launch_bounds__(256) void attn_pool(
    const float* __restrict__ out1,   // [B][T][1024]
    const float* __restrict__ aw,     // [1024]
    const float* __restrict__ ab,     // [1]
    float* __restrict__ enc)          // [B][1024]
{
  __shared__ float wbuf[1024];
  __shared__ float sc[1024];
  __shared__ float red[16];
  const int b = blockIdx.x;
  const int tid = threadIdx.x;
  const int wave = tid >> 6, lane = tid & 63;
  ((f32x4*)wbuf)[tid] = ((const f32x4*)aw)[tid];
  __syncthreads();
  const float* ob = out1 + (size_t)b * T_ * 1024;
  const float bias = ab[0];

  for (int t = wave; t < T_; t += 4){
    const float* row = ob + (size_t)t * 1024;
    float s = dot4(((const f32x4*)row)[lane],       ((const f32x4*)wbuf)[lane])
            + dot4(((const f32x4*)row)[lane + 64],  ((const f32x4*)wbuf)[lane + 64])
            + dot4(((const f32x4*)row)[lane + 128], ((const f32x4*)wbuf)[lane + 128])
            + dot4(((const f32x4*)row)[lane + 192], ((const f32x4*)wbuf)[lane + 192]);
    #pragma unroll
    for (int o = 32; o > 0; o >>= 1) s += __shfl_xor(s, o, 64);
    if (lane == 0) sc[t] = s + bias;
  }
  __syncthreads();

  float m = -1e30f;
  for (int i = tid; i < 1024; i += 256) m = fmaxf(m, sc[i]);
  #pragma unroll
  for (int o = 32; o > 0; o >>= 1) m = fmaxf(m, __shfl_xor(m, o, 64));
  if (lane == 0) red[wave] = m;
  __syncthreads();
  m = fmaxf(fmaxf(red[0], red[1]), fmaxf(red[2], red[3]));

  float ssum = 0.f;
  for (int i = tid; i < 1024; i += 256){
    float p = __expf(sc[i] - m);
    sc[i] = p;
    ssum += p;
  }
  #pragma unroll
  for (int o = 32; o > 0; o >>= 1) ssum += __shfl_xor(ssum, o, 64);
  if (lane == 0) red[8 + wave] = ssum;
  __syncthreads();
  float inv = 1.0f / (red[8] + red[9] + red[10] + red[11]);

  f32x4 a = {0.f,0.f,0.f,0.f};
  for (int t = 0; t < T_; t++){
    f32x4 v = *(const f32x4*)(ob + (size_t)t * 1024 + tid * 4);
    float p = sc[t];
    a[0] += p * v[0]; a[1] += p * v[1]; a[2] += p * v[2]; a[3] += p * v[3];
  }
  f32x4 r = { a[0]*inv, a[1]*inv, a[2]*inv, a[3]*inv };
  *(f32x4*)(enc + (size_t)b * 1024 + tid * 4) = r;
}

// ---------------- host ----------------
extern "C" void kernel_launch(void* const* d_in, const int* in_sizes, int n_in,
                              void* d_out, int out_size, void* d_ws, size_t ws_size,
                              hipStream_t stream)
{
  const float* x        = (const float*)d_in[0];
  const float* w_ih_l0  = (const float*)d_in[1];
  const float* w_hh_l0  = (const float*)d_in[2];
  const float* b_ih_l0  = (const float*)d_in[3];
  const float* b_hh_l0  = (const float*)d_in[4];
  const float* w_ih_l0r = (const float*)d_in[5];
  const float* w_hh_l0r = (const float*)d_in[6];
  const float* b_ih_l0r = (const float*)d_in[7];
  const float* b_hh_l0r = (const float*)d_in[8];
  const float* w_ih_l1  = (const float*)d_in[9];
  const float* w_hh_l1  = (const float*)d_in[10];
  const float* b_ih_l1  = (const float*)d_in[11];
  const float* b_hh_l1  = (const float*)d_in[12];
  const float* w_ih_l1r = (const float*)d_in[13];
  const float* w_hh_l1r = (const float*)d_in[14];
  const float* b_ih_l1r = (const float*)d_in[15];
  const float* b_hh_l1r = (const float*)d_in[16];
  const float* attn_w   = (const float*)d_in[17];
  const float* attn_b   = (const float*)d_in[18];
  float* enc = (float*)d_out;

  char* ws = (char*)d_ws;
  size_t off = 0;
  auto alloc = [&](size_t bytes) -> void* {
    void* p = ws + off;
    off += (bytes + 255) & ~(size_t)255;
    return p;
  };
  ushort_t* Ahi  = (ushort_t*)alloc((size_t)M_ * 2048 * 2);
  ushort_t* Alo  = (ushort_t*)alloc((size_t)M_ * 2048 * 2);
  ushort_t* Whi0 = (ushort_t*)alloc((size_t)2048 * 2048 * 2);
  ushort_t* Wlo0 = (ushort_t*)alloc((size_t)2048 * 2048 * 2);
  ushort_t* Whi1 = (ushort_t*)alloc((size_t)2048 * 2048 * 2);
  ushort_t* Wlo1 = (ushort_t*)alloc((size_t)2048 * 2048 * 2);
  float*    xg   = (float*)alloc((size_t)2 * M_ * NG * 4);
  float*    outb = (float*)alloc((size_t)M_ * 1024 * 4);
  u64*      hbuf = (u64*)alloc((size_t)2 * 2 * 2 * 8192 * 8);   // [layer][dir][parity][16][512]
  unsigned* flags= (unsigned*)alloc((size_t)2 * 2 * NBLK_DIR * FLG_LINE * 4); // [layer][dir][blk][line]
  if (off > ws_size){
    fprintf(stderr, "kernel_launch: workspace too small: need %zu have %zu\n", off, ws_size);
    return;
  }

  // zero tagged h buffers + flag counters every call (replay-deterministic)
  {
    int n = (int)((size_t)2 * 2 * 2 * 8192 * 8 / 4) + 2 * 2 * NBLK_DIR * FLG_LINE;
    zero_u32<<<(n + 255) / 256, 256, 0, stream>>>((unsigned*)hbuf, n);
  }

  // ---- layer 0 ----
  split_f32_bf16<<<2048, 256, 0, stream>>>(x, Ahi, Alo, M_ * 2048 / 4);
  split_f32_bf16<<<512, 256, 0, stream>>>(w_ih_l0,  Whi0, Wlo0, 2048 * 2048 / 4);
  split_f32_bf16<<<512, 256, 0, stream>>>(w_ih_l0r, Whi1, Wlo1, 2048 * 2048 / 4);
  gemm_xg<<<dim3(16, 128, 2), 256, 0, stream>>>(
      Ahi, Alo, Whi0, Wlo0, Whi1, Wlo1,
      b_ih_l0, b_hh_l0, b_ih_l0r, b_hh_l0r,
      xg, xg + (size_t)M_ * NG, M_, NG, 2048);
  lstm_layer<<<32, 512, 0, stream>>>(w_hh_l0, w_hh_l0r, xg, hbuf, flags,
                                     nullptr, Ahi, Alo);
  // ---- layer 1 ----
  split_f32_bf16<<<512, 256, 0, stream>>>(w_ih_l1,  Whi0, Wlo0, 2048 * 1024 / 4);
  split_f32_bf16<<<512, 256, 0, stream>>>(w_ih_l1r, Whi1, Wlo1, 2048 * 1024 / 4);
  gemm_xg<<<dim3(16, 128, 2), 256, 0, stream>>>(
      Ahi, Alo, Whi0, Wlo0, Whi1, Wlo1,
      b_ih_l1, b_hh_l1, b_ih_l1r, b_hh_l1r,
      xg, xg + (size_t)M_ * NG, M_, NG, 1024);
  lstm_layer<<<32, 512, 0, stream>>>(w_hh_l1, w_hh_l1r, xg,
                                     hbuf + (size_t)2 * 2 * 8192,
                                     flags + (size_t)2 * NBLK_DIR * FLG_LINE,
                                     outb, nullptr, nullptr);
  // ---- attention pooling ----
  attn_pool<<<16, 256, 0, stream>>>(outb, attn_w, attn_b, enc);
}

// Round 11
// 10589.700 us; speedup vs baseline: 2.0780x; 1.1589x over previous
//
#include <hip/hip_runtime.h>
#include <hip/hip_bf16.h>
#include <cstdio>

typedef unsigned short ushort_t;
typedef unsigned long long u64;
typedef __attribute__((ext_vector_type(4))) float f32x4;
typedef __attribute__((ext_vector_type(4))) unsigned int u32x4;
typedef __attribute__((ext_vector_type(8))) __bf16 bf16x8;
typedef __attribute__((ext_vector_type(8))) unsigned short u16x8;
typedef __attribute__((ext_vector_type(4))) unsigned short u16x4;

#define B_  16
#define T_  1024
#define H_  512
#define NG  2048          // 4*H
#define M_  (B_*T_)       // 16384
#define NBLK_DIR 16       // lstm blocks per direction
#define FLG_STRIDE 64     // u32s per (dir) flag row (16 used, 256B padded)

__device__ inline unsigned short f2bf_rne(float f){
  union { float f; unsigned int u; } v; v.f = f;
  unsigned int u = v.u;
  unsigned int r = (u + 0x7fffu + ((u >> 16) & 1u)) >> 16;
  return (unsigned short)r;
}
__device__ inline float bf2f(unsigned short s){
  union { unsigned int u; float f; } v; v.u = ((unsigned int)s) << 16;
  return v.f;
}
__device__ inline float sigm_f(float x){
  return 1.0f / (1.0f + __expf(-x));
}
__device__ inline float tanh_f(float x){
  return 1.0f - 2.0f / (__expf(2.0f * x) + 1.0f);
}

__global__ void zero_u32(unsigned* __restrict__ p, int n){
  int i = blockIdx.x * blockDim.x + threadIdx.x;
  if (i < n) p[i] = 0u;
}

// ---------------- split f32 -> bf16 hi + bf16 lo ----------------
__global__ void split_f32_bf16(const float* __restrict__ src,
                               ushort_t* __restrict__ hi, ushort_t* __restrict__ lo,
                               int n4){
  int i = blockIdx.x * blockDim.x + threadIdx.x;
  int stride = gridDim.x * blockDim.x;
  for (; i < n4; i += stride){
    f32x4 v = ((const f32x4*)src)[i];
    u16x4 h4, l4;
    #pragma unroll
    for (int j = 0; j < 4; j++){
      unsigned short h = f2bf_rne(v[j]);
      h4[j] = h;
      l4[j] = f2bf_rne(v[j] - bf2f(h));
    }
    ((u16x4*)hi)[i] = h4;
    ((u16x4*)lo)[i] = l4;
  }
}

// ---------------- split-bf16 MFMA GEMM: C = A * B^T + bias ----------------
__global__ __launch_bounds__(256) void gemm_xg(
    const ushort_t* __restrict__ Ahi, const ushort_t* __restrict__ Alo,
    const ushort_t* __restrict__ Bhi0, const ushort_t* __restrict__ Blo0,
    const ushort_t* __restrict__ Bhi1, const ushort_t* __restrict__ Blo1,
    const float* __restrict__ bi0, const float* __restrict__ bh0,
    const float* __restrict__ bi1, const float* __restrict__ bh1,
    float* __restrict__ C0, float* __restrict__ C1,
    int M, int N, int K)
{
  __shared__ ushort_t As[128*32];
  __shared__ ushort_t Bs[128*32];
  const int tid  = threadIdx.x;
  const int wave = tid >> 6, lane = tid & 63;
  const int l15 = lane & 15, l4 = lane >> 4;
  const int wr = wave >> 1, wc = wave & 1;
  const int n0 = blockIdx.x * 128, m0 = blockIdx.y * 128;
  const int dir = blockIdx.z;
  const ushort_t* Bhi = dir ? Bhi1 : Bhi0;
  const ushort_t* Blo = dir ? Blo1 : Blo0;
  const float* bia = dir ? bi1 : bi0;
  const float* bib = dir ? bh1 : bh0;
  float* C = dir ? C1 : C0;

  f32x4 acc[4][4];
  #pragma unroll
  for (int i = 0; i < 4; i++)
    #pragma unroll
    for (int j = 0; j < 4; j++) acc[i][j] = (f32x4){0.f,0.f,0.f,0.f};

  const int e0 = tid, e1 = 256 + tid;
  const int row0 = e0 >> 2, c80 = (e0 & 3) * 8;
  const int row1 = e1 >> 2, c81 = (e1 & 3) * 8;

  for (int seg = 0; seg < 3; ++seg){
    const ushort_t* Ap = (seg == 2) ? Alo : Ahi;
    const ushort_t* Bp = (seg == 1) ? Blo : Bhi;
    for (int kt = 0; kt < K; kt += 32){
      __builtin_amdgcn_global_load_lds(
        (const __attribute__((address_space(1))) unsigned int*)(Ap + (size_t)(m0 + row0) * K + kt + c80),
        (__attribute__((address_space(3))) unsigned int*)(As + e0 * 8), 16, 0, 0);
      __builtin_amdgcn_global_load_lds(
        (const __attribute__((address_space(1))) unsigned int*)(Bp + (size_t)(n0 + row0) * K + kt + c80),
        (__attribute__((address_space(3))) unsigned int*)(Bs + e0 * 8), 16, 0, 0);
      __builtin_amdgcn_global_load_lds(
        (const __attribute__((address_space(1))) unsigned int*)(Ap + (size_t)(m0 + row1) * K + kt + c81),
        (__attribute__((address_space(3))) unsigned int*)(As + e1 * 8), 16, 0, 0);
      __builtin_amdgcn_global_load_lds(
        (const __attribute__((address_space(1))) unsigned int*)(Bp + (size_t)(n0 + row1) * K + kt + c81),
        (__attribute__((address_space(3))) unsigned int*)(Bs + e1 * 8), 16, 0, 0);
      __syncthreads();
      bf16x8 af[4], bfr[4];
      #pragma unroll
      for (int m = 0; m < 4; m++)
        af[m] = *(const bf16x8*)(As + (wr*64 + m*16 + l15) * 32 + l4 * 8);
      #pragma unroll
      for (int n = 0; n < 4; n++)
        bfr[n] = *(const bf16x8*)(Bs + (wc*64 + n*16 + l15) * 32 + l4 * 8);
      #pragma unroll
      for (int m = 0; m < 4; m++)
        #pragma unroll
        for (int n = 0; n < 4; n++)
          acc[m][n] = __builtin_amdgcn_mfma_f32_16x16x32_bf16(af[m], bfr[n], acc[m][n], 0, 0, 0);
      __syncthreads();
    }
  }
  #pragma unroll
  for (int m = 0; m < 4; m++)
    #pragma unroll
    for (int n = 0; n < 4; n++){
      int col = n0 + wc*64 + n*16 + l15;
      float bias = bia[col] + bib[col];
      #pragma unroll
      for (int r = 0; r < 4; r++){
        int row = m0 + wr*64 + m*16 + l4*4 + r;
        C[(size_t)row * N + col] = acc[m][n][r] + bias;
      }
    }
}

// ---------------- persistent bidirectional LSTM layer (untagged u32 exchange) ----------------
// 32 blocks x 512 threads. Block = (dir = blk>>4, cb = blk&15), owns h-cols [32*cb,+32).
// hbuf: [dir][parity][cb][512] u32 = (bf16hi | bf16lo<<16), slot = batch*32 + col_within.
//  producer store: chunk + tid  -> 2KB contiguous per block
//  consumer sweep: thread reads 8 contiguous u64 (64B); wave = 4KB linear. No tags.
// PUBLISH: data stores -> __syncthreads() (compiler drains vmcnt before s_barrier ->
// agent-scope stores acked at coherence point; proven by r10) -> tid0 monotone flag
// store on ONE 64B line of 16 flags (r7's proven poll target).
// Overwrite safety (no tags needed): block writes h_{t+1} over h_{t-1} only after its
// step-t poll saw all flags >= t+1, which transitively implies every block finished
// reading h_{t-1}.
__global__ __launch_bounds__(512, 1) void lstm_layer(
    const float* __restrict__ whh_fwd, const float* __restrict__ whh_bwd,
    const float* __restrict__ xg,      // [2][M_][NG], m = b*T + t
    unsigned* __restrict__ hbuf,       // [2 dir][2 parity][16][512] u32
    unsigned* __restrict__ flags,      // [2 dir][FLG_STRIDE] u32 (16 used)
    float* __restrict__ out_f32,       // [B][T][1024] or null
    ushort_t* __restrict__ out_hi,     // [B][T][1024] or null (split output)
    ushort_t* __restrict__ out_lo)
{
  const int dir = blockIdx.x >> 4;
  const int cb  = blockIdx.x & 15;
  const int tid = threadIdx.x;
  const int wave = tid >> 6, lane = tid & 63;
  const int gate = wave >> 1, ch = wave & 1;
  const int l15 = lane & 15, l4 = lane >> 4;
  const float* whh = dir ? whh_bwd : whh_fwd;
  unsigned* hb = hbuf + (size_t)dir * 2 * 8192;     // [parity][16][512] u32
  unsigned* flg = flags + (size_t)dir * FLG_STRIDE; // 16 u32, one line

  __shared__ ushort_t hfhi[8192];   // fragment order: 16B unit u = colblk*16 + batch
  __shared__ ushort_t hflo[8192];
  __shared__ float gbuf[4][16][33];

  // --- W_hh fragments (split bf16): wave rows gate*512 + cb*32 + ch*16 + l15 ---
  bf16x8 Whi[16], Wlo[16];
  {
    const int wrow = gate * 512 + cb * 32 + ch * 16 + l15;
    const float* p0 = whh + (size_t)wrow * 512;
    #pragma unroll
    for (int s = 0; s < 16; s++){
      const float* p = p0 + s * 32 + l4 * 8;
      f32x4 va = *(const f32x4*)(p);
      f32x4 vb = *(const f32x4*)(p + 4);
      u16x8 th, tl;
      #pragma unroll
      for (int j = 0; j < 4; j++){
        unsigned short h = f2bf_rne(va[j]);
        th[j] = h; tl[j] = f2bf_rne(va[j] - bf2f(h));
        unsigned short h2 = f2bf_rne(vb[j]);
        th[4+j] = h2; tl[4+j] = f2bf_rne(vb[j] - bf2f(h2));
      }
      Whi[s] = __builtin_bit_cast(bf16x8, th);
      Wlo[s] = __builtin_bit_cast(bf16x8, tl);
    }
  }

  const int eb = tid >> 5, ecl = tid & 31, ecol = cb * 32 + ecl;

  // consumer sweep: thread reads chunk p, batch b, 16 cols starting at cw0
  const int p   = tid >> 5;
  const int b5  = tid & 31;
  const int cb_b  = b5 >> 1;              // batch this thread unpacks
  const int lo1 = b5 & 1;                 // which 16-col half of the chunk row
  const int unitBase = (p * 4 + lo1 * 2) * 16 + cb_b;   // fragment unit of first colblk

  // --- init: publish own slice of h_0 (zeros); barrier-publish then flag=1 ---
  __hip_atomic_store(&hb[cb * 512 + tid], 0u, __ATOMIC_RELAXED, __HIP_MEMORY_SCOPE_AGENT);
  __syncthreads();   // drains vmcnt: stores visible at coherence point
  if (tid == 0)
    __hip_atomic_store(&flg[cb], 1u, __ATOMIC_RELAXED, __HIP_MEMORY_SCOPE_AGENT);

  float c_state = 0.0f;

  for (int t = 0; t < T_; ++t){
    // A) prefetch xg for this step (latency hides under the poll)
    const int t_eff = dir ? (T_ - 1 - t) : t;
    const float* xgp = xg + ((size_t)dir * M_ + (size_t)eb * T_ + t_eff) * NG + ecol;
    float xi = xgp[0];
    float xf = xgp[512];
    float xgg = xgp[1024];
    float xo = xgp[1536];

    // B) slim poll: 16 lanes watch one 64B flag line (monotone values)
    const unsigned want = (unsigned)(t + 1);
    if (tid < NBLK_DIR){
      while (__hip_atomic_load(&flg[tid], __ATOMIC_RELAXED, __HIP_MEMORY_SCOPE_AGENT) < want)
        __builtin_amdgcn_s_sleep(1);
    }
    __syncthreads();

    // C) bulk sweep: 8 contiguous u64 (64B/thread; wave = 4KB linear). Flag implies fresh.
    const u64* src = (const u64*)(hb + (size_t)(t & 1) * 8192) + (size_t)p * 256 + (size_t)b5 * 8;
    u64 v[8];
    #pragma unroll
    for (int k = 0; k < 8; k++)
      v[k] = __hip_atomic_load(&src[k], __ATOMIC_RELAXED, __HIP_MEMORY_SCOPE_AGENT);

    // unpack into fragment LDS: 2 units (b128) per array
    {
      u32x4 wh0, wh1, wl0, wl1;
      #pragma unroll
      for (int k = 0; k < 4; k++){
        unsigned d0 = (unsigned)v[k], d1 = (unsigned)(v[k] >> 32);
        wh0[k] = (d0 & 0xffffu) | (d1 << 16);
        wl0[k] = (d0 >> 16) | (d1 & 0xffff0000u);
      }
      #pragma unroll
      for (int k = 0; k < 4; k++){
        unsigned d0 = (unsigned)v[4 + k], d1 = (unsigned)(v[4 + k] >> 32);
        wh1[k] = (d0 & 0xffffu) | (d1 << 16);
        wl1[k] = (d0 >> 16) | (d1 & 0xffff0000u);
      }
      ((u32x4*)hfhi)[unitBase]      = wh0;
      ((u32x4*)hfhi)[unitBase + 16] = wh1;
      ((u32x4*)hflo)[unitBase]      = wl0;
      ((u32x4*)hflo)[unitBase + 16] = wl1;
    }
    __syncthreads();

    // D) gates: 3 independent MFMA chains (r5's proven fragment-read layout)
    {
      f32x4 a0 = {0.f,0.f,0.f,0.f}, a1 = a0, a2 = a0;
      #pragma unroll
      for (int s = 0; s < 16; s++){
        bf16x8 ah = *(const bf16x8*)&hfhi[(s * 64 + l4 * 16 + l15) * 8];
        bf16x8 al = *(const bf16x8*)&hflo[(s * 64 + l4 * 16 + l15) * 8];
        a0 = __builtin_amdgcn_mfma_f32_16x16x32_bf16(ah, Whi[s], a0, 0, 0, 0);
        a1 = __builtin_amdgcn_mfma_f32_16x16x32_bf16(ah, Wlo[s], a1, 0, 0, 0);
        a2 = __builtin_amdgcn_mfma_f32_16x16x32_bf16(al, Whi[s], a2, 0, 0, 0);
      }
      f32x4 acc = a0 + a1;
      acc = acc + a2;
      #pragma unroll
      for (int r = 0; r < 4; r++)
        gbuf[gate][l4 * 4 + r][ch * 16 + l15] = acc[r];
    }
    __syncthreads();

    // E) cell; data store -> barrier-publish -> flag; out stores last
    float h; unsigned short hh, hl; size_t oidx;
    {
      float pi = gbuf[0][eb][ecl] + xi;
      float pf = gbuf[1][eb][ecl] + xf;
      float pg = gbuf[2][eb][ecl] + xgg;
      float po = gbuf[3][eb][ecl] + xo;
      float ig = sigm_f(pi);
      float fg = sigm_f(pf);
      float gg = tanh_f(pg);
      float og = sigm_f(po);
      c_state = fg * c_state + ig * gg;
      h = og * tanh_f(c_state);
      hh = f2bf_rne(h);
      hl = f2bf_rne(h - bf2f(hh));
      oidx = ((size_t)eb * T_ + t_eff) * 1024 + dir * 512 + ecol;
      __hip_atomic_store(&hb[(size_t)((t + 1) & 1) * 8192 + cb * 512 + tid],
                         (unsigned)hh | ((unsigned)hl << 16),
                         __ATOMIC_RELAXED, __HIP_MEMORY_SCOPE_AGENT);
    }
    __syncthreads();   // drains vmcnt: this block's h stores visible before flag
    if (tid == 0)
      __hip_atomic_store(&flg[cb], (unsigned)(t + 2), __ATOMIC_RELAXED, __HIP_MEMORY_SCOPE_AGENT);
    if (out_f32) out_f32[oidx] = h;
    if (out_hi){ out_hi[oidx] = hh; out_lo[oidx] = hl; }
  }
}

// ---------------- attention pooling ----------------
__device__ inline float dot4(f32x4 a, f32x4 b){
  return a[0]*b[0] + a[1]*b[1] + a[2]*b[2] + a[3]*b[3];
}

__global__ __launch_bounds__(256) void attn_pool(
    const float* __restrict__ out1,   // [B][T][1024]
    const float* __restrict__ aw,     // [1024]
    const float* __restrict__ ab,     // [1]
    float* __restrict__ enc)          // [B][1024]
{
  __shared__ float wbuf[1024];
  __shared__ float sc[1024];
  __shared__ float red[16];
  const int b = blockIdx.x;
  const int tid = threadIdx.x;
  const int wave = tid >> 6, lane = tid & 63;
  ((f32x4*)wbuf)[tid] = ((const f32x4*)aw)[tid];
  __syncthreads();
  const float* ob = out1 + (size_t)b * T_ * 1024;
  const float bias = ab[0];

  for (int t = wave; t < T_; t += 4){
    const float* row = ob + (size_t)t * 1024;
    float s = dot4(((const f32x4*)row)[lane],       ((const f32x4*)wbuf)[lane])
            + dot4(((const f32x4*)row)[lane + 64],  ((const f32x4*)wbuf)[lane + 64])
            + dot4(((const f32x4*)row)[lane + 128], ((const f32x4*)wbuf)[lane + 128])
            + dot4(((const f32x4*)row)[lane + 192], ((const f32x4*)wbuf)[lane + 192]);
    #pragma unroll
    for (int o = 32; o > 0; o >>= 1) s += __shfl_xor(s, o, 64);
    if (lane == 0) sc[t] = s + bias;
  }
  __syncthreads();

  float m = -1e30f;
  for (int i = tid; i < 1024; i += 256) m = fmaxf(m, sc[i]);
  #pragma unroll
  for (int o = 32; o > 0; o >>= 1) m = fmaxf(m, __shfl_xor(m, o, 64));
  if (lane == 0) red[wave] = m;
  __syncthreads();
  m = fmaxf(fmaxf(red[0], red[1]), fmaxf(red[2], red[3]));

  float ssum = 0.f;
  for (int i = tid; i < 1024; i += 256){
    float p = __expf(sc[i] - m);
    sc[i] = p;
    ssum += p;
  }
  #pragma unroll
  for (int o = 32; o > 0; o >>= 1) ssum += __shfl_xor(ssum, o, 64);
  if (lane == 0) red[8 + wave] = ssum;
  __syncthreads();
  float inv = 1.0f / (red[8] + red[9] + red[10] + red[11]);

  f32x4 a = {0.f,0.f,0.f,0.f};
  for (int t = 0; t < T_; t++){
    f32x4 v = *(const f32x4*)(ob + (size_t)t * 1024 + tid * 4);
    float p = sc[t];
    a[0] += p * v[0]; a[1] += p * v[1]; a[2] += p * v[2]; a[3] += p * v[3];
  }
  f32x4 r = { a[0]*inv, a[1]*inv, a[2]*inv, a[3]*inv };
  *(f32x4*)(enc + (size_t)b * 1024 + tid * 4) = r;
}

// ---------------- host ----------------
extern "C" void kernel_launch(void* const* d_in, const int* in_sizes, int n_in,
                              void* d_out, int out_size, void* d_ws, size_t ws_size,
                              hipStream_t stream)
{
  const float* x        = (const float*)d_in[0];
  const float* w_ih_l0  = (const float*)d_in[1];
  const float* w_hh_l0  = (const float*)d_in[2];
  const float* b_ih_l0  = (const float*)d_in[3];
  const float* b_hh_l0  = (const float*)d_in[4];
  const float* w_ih_l0r = (const float*)d_in[5];
  const float* w_hh_l0r = (const float*)d_in[6];
  const float* b_ih_l0r = (const float*)d_in[7];
  const float* b_hh_l0r = (const float*)d_in[8];
  const float* w_ih_l1  = (const float*)d_in[9];
  const float* w_hh_l1  = (const float*)d_in[10];
  const float* b_ih_l1  = (const float*)d_in[11];
  const float* b_hh_l1  = (const float*)d_in[12];
  const float* w_ih_l1r = (const float*)d_in[13];
  const float* w_hh_l1r = (const float*)d_in[14];
  const float* b_ih_l1r = (const float*)d_in[15];
  const float* b_hh_l1r = (const float*)d_in[16];
  const float* attn_w   = (const float*)d_in[17];
  const float* attn_b   = (const float*)d_in[18];
  float* enc = (float*)d_out;

  char* ws = (char*)d_ws;
  size_t off = 0;
  auto alloc = [&](size_t bytes) -> void* {
    void* p = ws + off;
    off += (bytes + 255) & ~(size_t)255;
    return p;
  };
  ushort_t* Ahi  = (ushort_t*)alloc((size_t)M_ * 2048 * 2);
  ushort_t* Alo  = (ushort_t*)alloc((size_t)M_ * 2048 * 2);
  ushort_t* Whi0 = (ushort_t*)alloc((size_t)2048 * 2048 * 2);
  ushort_t* Wlo0 = (ushort_t*)alloc((size_t)2048 * 2048 * 2);
  ushort_t* Whi1 = (ushort_t*)alloc((size_t)2048 * 2048 * 2);
  ushort_t* Wlo1 = (ushort_t*)alloc((size_t)2048 * 2048 * 2);
  float*    xg   = (float*)alloc((size_t)2 * M_ * NG * 4);
  float*    outb = (float*)alloc((size_t)M_ * 1024 * 4);
  unsigned* hbuf = (unsigned*)alloc((size_t)2 * 2 * 2 * 8192 * 4);  // [layer][dir][parity][16][512] u32
  unsigned* flags= (unsigned*)alloc((size_t)2 * 2 * FLG_STRIDE * 4); // [layer][dir][..]
  if (off > ws_size){
    fprintf(stderr, "kernel_launch: workspace too small: need %zu have %zu\n", off, ws_size);
    return;
  }

  // zero h buffers + flags every call (replay-deterministic)
  {
    int n = 2 * 2 * 2 * 8192 + 2 * 2 * FLG_STRIDE;
    zero_u32<<<(n + 255) / 256, 256, 0, stream>>>(hbuf, n);
  }

  // ---- layer 0 ----
  split_f32_bf16<<<2048, 256, 0, stream>>>(x, Ahi, Alo, M_ * 2048 / 4);
  split_f32_bf16<<<512, 256, 0, stream>>>(w_ih_l0,  Whi0, Wlo0, 2048 * 2048 / 4);
  split_f32_bf16<<<512, 256, 0, stream>>>(w_ih_l0r, Whi1, Wlo1, 2048 * 2048 / 4);
  gemm_xg<<<dim3(16, 128, 2), 256, 0, stream>>>(
      Ahi, Alo, Whi0, Wlo0, Whi1, Wlo1,
      b_ih_l0, b_hh_l0, b_ih_l0r, b_hh_l0r,
      xg, xg + (size_t)M_ * NG, M_, NG, 2048);
  lstm_layer<<<32, 512, 0, stream>>>(w_hh_l0, w_hh_l0r, xg, hbuf, flags,
                                     nullptr, Ahi, Alo);
  // ---- layer 1 ----
  split_f32_bf16<<<512, 256, 0, stream>>>(w_ih_l1,  Whi0, Wlo0, 2048 * 1024 / 4);
  split_f32_bf16<<<512, 256, 0, stream>>>(w_ih_l1r, Whi1, Wlo1, 2048 * 1024 / 4);
  gemm_xg<<<dim3(16, 128, 2), 256, 0, stream>>>(
      Ahi, Alo, Whi0, Wlo0, Whi1, Wlo1,
      b_ih_l1, b_hh_l1, b_ih_l1r, b_hh_l1r,
      xg, xg + (size_t)M_ * NG, M_, NG, 1024);
  lstm_layer<<<32, 512, 0, stream>>>(w_hh_l1, w_hh_l1r, xg,
                                     hbuf + (size_t)2 * 2 * 8192,
                                     flags + (size_t)2 * FLG_STRIDE,
                                     outb, nullptr, nullptr);
  // ---- attention pooling ----
  attn_pool<<<16, 256, 0, stream>>>(outb, attn_w, attn_b, enc);
}

// Round 12
// 10315.561 us; speedup vs baseline: 2.1332x; 1.0266x over previous
//
#include <hip/hip_runtime.h>
#include <hip/hip_bf16.h>
#include <cstdio>

typedef unsigned short ushort_t;
typedef unsigned long long u64;
typedef __attribute__((ext_vector_type(4))) float f32x4;
typedef __attribute__((ext_vector_type(4))) unsigned int u32x4;
typedef __attribute__((ext_vector_type(8))) __bf16 bf16x8;
typedef __attribute__((ext_vector_type(8))) unsigned short u16x8;
typedef __attribute__((ext_vector_type(4))) unsigned short u16x4;

#define B_  16
#define T_  1024
#define H_  512
#define NG  2048          // 4*H
#define M_  (B_*T_)       // 16384
#define NBLK_DIR 16       // lstm blocks per direction
#define FLG_STRIDE 64     // u32s per (dir) flag row (16 used, 256B padded)

__device__ inline unsigned short f2bf_rne(float f){
  union { float f; unsigned int u; } v; v.f = f;
  unsigned int u = v.u;
  unsigned int r = (u + 0x7fffu + ((u >> 16) & 1u)) >> 16;
  return (unsigned short)r;
}
__device__ inline float bf2f(unsigned short s){
  union { unsigned int u; float f; } v; v.u = ((unsigned int)s) << 16;
  return v.f;
}
__device__ inline float sigm_f(float x){
  return 1.0f / (1.0f + __expf(-x));
}
__device__ inline float tanh_f(float x){
  return 1.0f - 2.0f / (__expf(2.0f * x) + 1.0f);
}

__global__ void zero_u32(unsigned* __restrict__ p, int n){
  int i = blockIdx.x * blockDim.x + threadIdx.x;
  if (i < n) p[i] = 0u;
}

// ---------------- split f32 -> bf16 hi + bf16 lo ----------------
__global__ void split_f32_bf16(const float* __restrict__ src,
                               ushort_t* __restrict__ hi, ushort_t* __restrict__ lo,
                               int n4){
  int i = blockIdx.x * blockDim.x + threadIdx.x;
  int stride = gridDim.x * blockDim.x;
  for (; i < n4; i += stride){
    f32x4 v = ((const f32x4*)src)[i];
    u16x4 h4, l4;
    #pragma unroll
    for (int j = 0; j < 4; j++){
      unsigned short h = f2bf_rne(v[j]);
      h4[j] = h;
      l4[j] = f2bf_rne(v[j] - bf2f(h));
    }
    ((u16x4*)hi)[i] = h4;
    ((u16x4*)lo)[i] = l4;
  }
}

// ---------------- split-bf16 MFMA GEMM: C = A * B^T + bias ----------------
__global__ __launch_bounds__(256) void gemm_xg(
    const ushort_t* __restrict__ Ahi, const ushort_t* __restrict__ Alo,
    const ushort_t* __restrict__ Bhi0, const ushort_t* __restrict__ Blo0,
    const ushort_t* __restrict__ Bhi1, const ushort_t* __restrict__ Blo1,
    const float* __restrict__ bi0, const float* __restrict__ bh0,
    const float* __restrict__ bi1, const float* __restrict__ bh1,
    float* __restrict__ C0, float* __restrict__ C1,
    int M, int N, int K)
{
  __shared__ ushort_t As[128*32];
  __shared__ ushort_t Bs[128*32];
  const int tid  = threadIdx.x;
  const int wave = tid >> 6, lane = tid & 63;
  const int l15 = lane & 15, l4 = lane >> 4;
  const int wr = wave >> 1, wc = wave & 1;
  const int n0 = blockIdx.x * 128, m0 = blockIdx.y * 128;
  const int dir = blockIdx.z;
  const ushort_t* Bhi = dir ? Bhi1 : Bhi0;
  const ushort_t* Blo = dir ? Blo1 : Blo0;
  const float* bia = dir ? bi1 : bi0;
  const float* bib = dir ? bh1 : bh0;
  float* C = dir ? C1 : C0;

  f32x4 acc[4][4];
  #pragma unroll
  for (int i = 0; i < 4; i++)
    #pragma unroll
    for (int j = 0; j < 4; j++) acc[i][j] = (f32x4){0.f,0.f,0.f,0.f};

  const int e0 = tid, e1 = 256 + tid;
  const int row0 = e0 >> 2, c80 = (e0 & 3) * 8;
  const int row1 = e1 >> 2, c81 = (e1 & 3) * 8;

  for (int seg = 0; seg < 3; ++seg){
    const ushort_t* Ap = (seg == 2) ? Alo : Ahi;
    const ushort_t* Bp = (seg == 1) ? Blo : Bhi;
    for (int kt = 0; kt < K; kt += 32){
      __builtin_amdgcn_global_load_lds(
        (const __attribute__((address_space(1))) unsigned int*)(Ap + (size_t)(m0 + row0) * K + kt + c80),
        (__attribute__((address_space(3))) unsigned int*)(As + e0 * 8), 16, 0, 0);
      __builtin_amdgcn_global_load_lds(
        (const __attribute__((address_space(1))) unsigned int*)(Bp + (size_t)(n0 + row0) * K + kt + c80),
        (__attribute__((address_space(3))) unsigned int*)(Bs + e0 * 8), 16, 0, 0);
      __builtin_amdgcn_global_load_lds(
        (const __attribute__((address_space(1))) unsigned int*)(Ap + (size_t)(m0 + row1) * K + kt + c81),
        (__attribute__((address_space(3))) unsigned int*)(As + e1 * 8), 16, 0, 0);
      __builtin_amdgcn_global_load_lds(
        (const __attribute__((address_space(1))) unsigned int*)(Bp + (size_t)(n0 + row1) * K + kt + c81),
        (__attribute__((address_space(3))) unsigned int*)(Bs + e1 * 8), 16, 0, 0);
      __syncthreads();
      bf16x8 af[4], bfr[4];
      #pragma unroll
      for (int m = 0; m < 4; m++)
        af[m] = *(const bf16x8*)(As + (wr*64 + m*16 + l15) * 32 + l4 * 8);
      #pragma unroll
      for (int n = 0; n < 4; n++)
        bfr[n] = *(const bf16x8*)(Bs + (wc*64 + n*16 + l15) * 32 + l4 * 8);
      #pragma unroll
      for (int m = 0; m < 4; m++)
        #pragma unroll
        for (int n = 0; n < 4; n++)
          acc[m][n] = __builtin_amdgcn_mfma_f32_16x16x32_bf16(af[m], bfr[n], acc[m][n], 0, 0, 0);
      __syncthreads();
    }
  }
  #pragma unroll
  for (int m = 0; m < 4; m++)
    #pragma unroll
    for (int n = 0; n < 4; n++){
      int col = n0 + wc*64 + n*16 + l15;
      float bias = bia[col] + bib[col];
      #pragma unroll
      for (int r = 0; r < 4; r++){
        int row = m0 + wr*64 + m*16 + l4*4 + r;
        C[(size_t)row * N + col] = acc[m][n][r] + bias;
      }
    }
}

// ---------------- persistent bidirectional LSTM layer (untagged u32, token release) ----------------
// 32 blocks x 512 threads. Block = (dir = blk>>4, cb = blk&15), owns h-cols [32*cb,+32).
// hbuf: [dir][parity][cb][512] u32 = (bf16hi | bf16lo<<16), slot = batch*32 + col_within.
// Release path (NO post-poll barrier): wave 0 polls the 16-flag line, then release-stores
// a monotone LDS token; waves 1-7 acquire-spin on the token (cheap ds_read, no vmcnt
// drain) and proceed straight to their sweep slice. First vmcnt drain is the post-sweep
// barrier -> the step-top xg prefetch is finally overlapped instead of drained early.
// Safety unchanged: producer data-before-flag via the pre-flag __syncthreads (vmcnt
// drain); overwrite safety via the post-sweep barrier + transitive flag argument.
__global__ __launch_bounds__(512, 1) void lstm_layer(
    const float* __restrict__ whh_fwd, const float* __restrict__ whh_bwd,
    const float* __restrict__ xg,      // [2][M_][NG], m = b*T + t
    unsigned* __restrict__ hbuf,       // [2 dir][2 parity][16][512] u32
    unsigned* __restrict__ flags,      // [2 dir][FLG_STRIDE] u32 (16 used)
    float* __restrict__ out_f32,       // [B][T][1024] or null
    ushort_t* __restrict__ out_hi,     // [B][T][1024] or null (split output)
    ushort_t* __restrict__ out_lo)
{
  const int dir = blockIdx.x >> 4;
  const int cb  = blockIdx.x & 15;
  const int tid = threadIdx.x;
  const int wave = tid >> 6, lane = tid & 63;
  const int gate = wave >> 1, ch = wave & 1;
  const int l15 = lane & 15, l4 = lane >> 4;
  const float* whh = dir ? whh_bwd : whh_fwd;
  unsigned* hb = hbuf + (size_t)dir * 2 * 8192;     // [parity][16][512] u32
  unsigned* flg = flags + (size_t)dir * FLG_STRIDE; // 16 u32, one line

  __shared__ ushort_t hfhi[8192];   // fragment order: 16B unit u = colblk*16 + batch
  __shared__ ushort_t hflo[8192];
  __shared__ float gbuf[4][16][33];
  __shared__ unsigned s_token;

  // --- W_hh fragments (split bf16): wave rows gate*512 + cb*32 + ch*16 + l15 ---
  bf16x8 Whi[16], Wlo[16];
  {
    const int wrow = gate * 512 + cb * 32 + ch * 16 + l15;
    const float* p0 = whh + (size_t)wrow * 512;
    #pragma unroll
    for (int s = 0; s < 16; s++){
      const float* p = p0 + s * 32 + l4 * 8;
      f32x4 va = *(const f32x4*)(p);
      f32x4 vb = *(const f32x4*)(p + 4);
      u16x8 th, tl;
      #pragma unroll
      for (int j = 0; j < 4; j++){
        unsigned short h = f2bf_rne(va[j]);
        th[j] = h; tl[j] = f2bf_rne(va[j] - bf2f(h));
        unsigned short h2 = f2bf_rne(vb[j]);
        th[4+j] = h2; tl[4+j] = f2bf_rne(vb[j] - bf2f(h2));
      }
      Whi[s] = __builtin_bit_cast(bf16x8, th);
      Wlo[s] = __builtin_bit_cast(bf16x8, tl);
    }
  }

  const int eb = tid >> 5, ecl = tid & 31, ecol = cb * 32 + ecl;

  // consumer sweep: thread reads chunk p, batch b, 16 cols
  const int p   = tid >> 5;
  const int b5  = tid & 31;
  const int cb_b  = b5 >> 1;              // batch this thread unpacks
  const int lo1 = b5 & 1;                 // which 16-col half of the chunk row
  const int unitBase = (p * 4 + lo1 * 2) * 16 + cb_b;   // fragment unit of first colblk

  // --- init: token=0; publish own slice of h_0 (zeros); barrier-publish then flag=1 ---
  if (tid == 0) s_token = 0u;
  __hip_atomic_store(&hb[cb * 512 + tid], 0u, __ATOMIC_RELAXED, __HIP_MEMORY_SCOPE_AGENT);
  __syncthreads();   // drains vmcnt: stores visible at coherence point; token init visible
  if (tid == 0)
    __hip_atomic_store(&flg[cb], 1u, __ATOMIC_RELAXED, __HIP_MEMORY_SCOPE_AGENT);

  float c_state = 0.0f;

  for (int t = 0; t < T_; ++t){
    // A) prefetch xg for this step (first drain is now the post-sweep barrier)
    const int t_eff = dir ? (T_ - 1 - t) : t;
    const float* xgp = xg + ((size_t)dir * M_ + (size_t)eb * T_ + t_eff) * NG + ecol;
    float xi = xgp[0];
    float xf = xgp[512];
    float xgg = xgp[1024];
    float xo = xgp[1536];

    // B) release: wave 0 polls the global flag line; LDS token releases other waves
    const unsigned want = (unsigned)(t + 1);
    if (wave == 0){
      if (lane < NBLK_DIR){
        while (__hip_atomic_load(&flg[lane], __ATOMIC_RELAXED, __HIP_MEMORY_SCOPE_AGENT) < want)
          __builtin_amdgcn_s_sleep(1);
      }
      if (lane == 0)
        __hip_atomic_store(&s_token, want, __ATOMIC_RELEASE, __HIP_MEMORY_SCOPE_WORKGROUP);
    } else {
      while (__hip_atomic_load(&s_token, __ATOMIC_ACQUIRE, __HIP_MEMORY_SCOPE_WORKGROUP) < want)
        __builtin_amdgcn_s_sleep(1);
    }

    // C) per-wave bulk sweep: 8 contiguous u64 (64B/thread; wave = 4KB linear)
    const u64* src = (const u64*)(hb + (size_t)(t & 1) * 8192) + (size_t)p * 256 + (size_t)b5 * 8;
    u64 v[8];
    #pragma unroll
    for (int k = 0; k < 8; k++)
      v[k] = __hip_atomic_load(&src[k], __ATOMIC_RELAXED, __HIP_MEMORY_SCOPE_AGENT);

    // unpack into fragment LDS: 2 units (b128) per array
    {
      u32x4 wh0, wh1, wl0, wl1;
      #pragma unroll
      for (int k = 0; k < 4; k++){
        unsigned d0 = (unsigned)v[k], d1 = (unsigned)(v[k] >> 32);
        wh0[k] = (d0 & 0xffffu) | (d1 << 16);
        wl0[k] = (d0 >> 16) | (d1 & 0xffff0000u);
      }
      #pragma unroll
      for (int k = 0; k < 4; k++){
        unsigned d0 = (unsigned)v[4 + k], d1 = (unsigned)(v[4 + k] >> 32);
        wh1[k] = (d0 & 0xffffu) | (d1 << 16);
        wl1[k] = (d0 >> 16) | (d1 & 0xffff0000u);
      }
      ((u32x4*)hfhi)[unitBase]      = wh0;
      ((u32x4*)hfhi)[unitBase + 16] = wh1;
      ((u32x4*)hflo)[unitBase]      = wl0;
      ((u32x4*)hflo)[unitBase + 16] = wl1;
    }
    __syncthreads();   // barrier #2: LDS consistency; drains sweep + (hidden) xg loads

    // D) gates: 3 independent MFMA chains
    {
      f32x4 a0 = {0.f,0.f,0.f,0.f}, a1 = a0, a2 = a0;
      #pragma unroll
      for (int s = 0; s < 16; s++){
        bf16x8 ah = *(const bf16x8*)&hfhi[(s * 64 + l4 * 16 + l15) * 8];
        bf16x8 al = *(const bf16x8*)&hflo[(s * 64 + l4 * 16 + l15) * 8];
        a0 = __builtin_amdgcn_mfma_f32_16x16x32_bf16(ah, Whi[s], a0, 0, 0, 0);
        a1 = __builtin_amdgcn_mfma_f32_16x16x32_bf16(ah, Wlo[s], a1, 0, 0, 0);
        a2 = __builtin_amdgcn_mfma_f32_16x16x32_bf16(al, Whi[s], a2, 0, 0, 0);
      }
      f32x4 acc = a0 + a1;
      acc = acc + a2;
      #pragma unroll
      for (int r = 0; r < 4; r++)
        gbuf[gate][l4 * 4 + r][ch * 16 + l15] = acc[r];
    }
    __syncthreads();   // barrier #3: gbuf cross-wave

    // E) cell; data store -> barrier-publish -> flag; out stores last
    float h; unsigned short hh, hl; size_t oidx;
    {
      float pi = gbuf[0][eb][ecl] + xi;
      float pf = gbuf[1][eb][ecl] + xf;
      float pg = gbuf[2][eb][ecl] + xgg;
      float po = gbuf[3][eb][ecl] + xo;
      float ig = sigm_f(pi);
      float fg = sigm_f(pf);
      float gg = tanh_f(pg);
      float og = sigm_f(po);
      c_state = fg * c_state + ig * gg;
      h = og * tanh_f(c_state);
      hh = f2bf_rne(h);
      hl = f2bf_rne(h - bf2f(hh));
      oidx = ((size_t)eb * T_ + t_eff) * 1024 + dir * 512 + ecol;
      __hip_atomic_store(&hb[(size_t)((t + 1) & 1) * 8192 + cb * 512 + tid],
                         (unsigned)hh | ((unsigned)hl << 16),
                         __ATOMIC_RELAXED, __HIP_MEMORY_SCOPE_AGENT);
    }
    __syncthreads();   // barrier #4: drains vmcnt -> h stores visible before flag
    if (tid == 0)
      __hip_atomic_store(&flg[cb], (unsigned)(t + 2), __ATOMIC_RELAXED, __HIP_MEMORY_SCOPE_AGENT);
    if (out_f32) out_f32[oidx] = h;
    if (out_hi){ out_hi[oidx] = hh; out_lo[oidx] = hl; }
  }
}

// ---------------- attention pooling ----------------
__device__ inline float dot4(f32x4 a, f32x4 b){
  return a[0]*b[0] + a[1]*b[1] + a[2]*b[2] + a[3]*b[3];
}

__global__ __launch_bounds__(256) void attn_pool(
    const float* __restrict__ out1,   // [B][T][1024]
    const float* __restrict__ aw,     // [1024]
    const float* __restrict__ ab,     // [1]
    float* __restrict__ enc)          // [B][1024]
{
  __shared__ float wbuf[1024];
  __shared__ float sc[1024];
  __shared__ float red[16];
  const int b = blockIdx.x;
  const int tid = threadIdx.x;
  const int wave = tid >> 6, lane = tid & 63;
  ((f32x4*)wbuf)[tid] = ((const f32x4*)aw)[tid];
  __syncthreads();
  const float* ob = out1 + (size_t)b * T_ * 1024;
  const float bias = ab[0];

  for (int t = wave; t < T_; t += 4){
    const float* row = ob + (size_t)t * 1024;
    float s = dot4(((const f32x4*)row)[lane],       ((const f32x4*)wbuf)[lane])
            + dot4(((const f32x4*)row)[lane + 64],  ((const f32x4*)wbuf)[lane + 64])
            + dot4(((const f32x4*)row)[lane + 128], ((const f32x4*)wbuf)[lane + 128])
            + dot4(((const f32x4*)row)[lane + 192], ((const f32x4*)wbuf)[lane + 192]);
    #pragma unroll
    for (int o = 32; o > 0; o >>= 1) s += __shfl_xor(s, o, 64);
    if (lane == 0) sc[t] = s + bias;
  }
  __syncthreads();

  float m = -1e30f;
  for (int i = tid; i < 1024; i += 256) m = fmaxf(m, sc[i]);
  #pragma unroll
  for (int o = 32; o > 0; o >>= 1) m = fmaxf(m, __shfl_xor(m, o, 64));
  if (lane == 0) red[wave] = m;
  __syncthreads();
  m = fmaxf(fmaxf(red[0], red[1]), fmaxf(red[2], red[3]));

  float ssum = 0.f;
  for (int i = tid; i < 1024; i += 256){
    float p = __expf(sc[i] - m);
    sc[i] = p;
    ssum += p;
  }
  #pragma unroll
  for (int o = 32; o > 0; o >>= 1) ssum += __shfl_xor(ssum, o, 64);
  if (lane == 0) red[8 + wave] = ssum;
  __syncthreads();
  float inv = 1.0f / (red[8] + red[9] + red[10] + red[11]);

  f32x4 a = {0.f,0.f,0.f,0.f};
  for (int t = 0; t < T_; t++){
    f32x4 v = *(const f32x4*)(ob + (size_t)t * 1024 + tid * 4);
    float p = sc[t];
    a[0] += p * v[0]; a[1] += p * v[1]; a[2] += p * v[2]; a[3] += p * v[3];
  }
  f32x4 r = { a[0]*inv, a[1]*inv, a[2]*inv, a[3]*inv };
  *(f32x4*)(enc + (size_t)b * 1024 + tid * 4) = r;
}

// ---------------- host ----------------
extern "C" void kernel_launch(void* const* d_in, const int* in_sizes, int n_in,
                              void* d_out, int out_size, void* d_ws, size_t ws_size,
                              hipStream_t stream)
{
  const float* x        = (const float*)d_in[0];
  const float* w_ih_l0  = (const float*)d_in[1];
  const float* w_hh_l0  = (const float*)d_in[2];
  const float* b_ih_l0  = (const float*)d_in[3];
  const float* b_hh_l0  = (const float*)d_in[4];
  const float* w_ih_l0r = (const float*)d_in[5];
  const float* w_hh_l0r = (const float*)d_in[6];
  const float* b_ih_l0r = (const float*)d_in[7];
  const float* b_hh_l0r = (const float*)d_in[8];
  const float* w_ih_l1  = (const float*)d_in[9];
  const float* w_hh_l1  = (const float*)d_in[10];
  const float* b_ih_l1  = (const float*)d_in[11];
  const float* b_hh_l1  = (const float*)d_in[12];
  const float* w_ih_l1r = (const float*)d_in[13];
  const float* w_hh_l1r = (const float*)d_in[14];
  const float* b_ih_l1r = (const float*)d_in[15];
  const float* b_hh_l1r = (const float*)d_in[16];
  const float* attn_w   = (const float*)d_in[17];
  const float* attn_b   = (const float*)d_in[18];
  float* enc = (float*)d_out;

  char* ws = (char*)d_ws;
  size_t off = 0;
  auto alloc = [&](size_t bytes) -> void* {
    void* p = ws + off;
    off += (bytes + 255) & ~(size_t)255;
    return p;
  };
  ushort_t* Ahi  = (ushort_t*)alloc((size_t)M_ * 2048 * 2);
  ushort_t* Alo  = (ushort_t*)alloc((size_t)M_ * 2048 * 2);
  ushort_t* Whi0 = (ushort_t*)alloc((size_t)2048 * 2048 * 2);
  ushort_t* Wlo0 = (ushort_t*)alloc((size_t)2048 * 2048 * 2);
  ushort_t* Whi1 = (ushort_t*)alloc((size_t)2048 * 2048 * 2);
  ushort_t* Wlo1 = (ushort_t*)alloc((size_t)2048 * 2048 * 2);
  float*    xg   = (float*)alloc((size_t)2 * M_ * NG * 4);
  float*    outb = (float*)alloc((size_t)M_ * 1024 * 4);
  unsigned* hbuf = (unsigned*)alloc((size_t)2 * 2 * 2 * 8192 * 4);  // [layer][dir][parity][16][512] u32
  unsigned* flags= (unsigned*)alloc((size_t)2 * 2 * FLG_STRIDE * 4); // [layer][dir][..]
  if (off > ws_size){
    fprintf(stderr, "kernel_launch: workspace too small: need %zu have %zu\n", off, ws_size);
    return;
  }

  // zero h buffers + flags every call (replay-deterministic)
  {
    int n = 2 * 2 * 2 * 8192 + 2 * 2 * FLG_STRIDE;
    zero_u32<<<(n + 255) / 256, 256, 0, stream>>>(hbuf, n);
  }

  // ---- layer 0 ----
  split_f32_bf16<<<2048, 256, 0, stream>>>(x, Ahi, Alo, M_ * 2048 / 4);
  split_f32_bf16<<<512, 256, 0, stream>>>(w_ih_l0,  Whi0, Wlo0, 2048 * 2048 / 4);
  split_f32_bf16<<<512, 256, 0, stream>>>(w_ih_l0r, Whi1, Wlo1, 2048 * 2048 / 4);
  gemm_xg<<<dim3(16, 128, 2), 256, 0, stream>>>(
      Ahi, Alo, Whi0, Wlo0, Whi1, Wlo1,
      b_ih_l0, b_hh_l0, b_ih_l0r, b_hh_l0r,
      xg, xg + (size_t)M_ * NG, M_, NG, 2048);
  lstm_layer<<<32, 512, 0, stream>>>(w_hh_l0, w_hh_l0r, xg, hbuf, flags,
                                     nullptr, Ahi, Alo);
  // ---- layer 1 ----
  split_f32_bf16<<<512, 256, 0, stream>>>(w_ih_l1,  Whi0, Wlo0, 2048 * 1024 / 4);
  split_f32_bf16<<<512, 256, 0, stream>>>(w_ih_l1r, Whi1, Wlo1, 2048 * 1024 / 4);
  gemm_xg<<<dim3(16, 128, 2), 256, 0, stream>>>(
      Ahi, Alo, Whi0, Wlo0, Whi1, Wlo1,
      b_ih_l1, b_hh_l1, b_ih_l1r, b_hh_l1r,
      xg, xg + (size_t)M_ * NG, M_, NG, 1024);
  lstm_layer<<<32, 512, 0, stream>>>(w_hh_l1, w_hh_l1r, xg,
                                     hbuf + (size_t)2 * 2 * 8192,
                                     flags + (size_t)2 * FLG_STRIDE,
                                     outb, nullptr, nullptr);
  // ---- attention pooling ----
  attn_pool<<<16, 256, 0, stream>>>(outb, attn_w, attn_b, enc);
}

// Round 13
// 10061.562 us; speedup vs baseline: 2.1871x; 1.0252x over previous
//
#include <hip/hip_runtime.h>
#include <hip/hip_bf16.h>
#include <cstdio>

typedef unsigned short ushort_t;
typedef unsigned long long u64;
typedef __attribute__((ext_vector_type(4))) float f32x4;
typedef __attribute__((ext_vector_type(4))) unsigned int u32x4;
typedef __attribute__((ext_vector_type(8))) __bf16 bf16x8;
typedef __attribute__((ext_vector_type(8))) unsigned short u16x8;
typedef __attribute__((ext_vector_type(4))) unsigned short u16x4;

#define B_  16
#define T_  1024
#define H_  512
#define NG  2048          // 4*H
#define M_  (B_*T_)       // 16384
#define NBLK_DIR 16       // lstm worker blocks per direction
#define FLG_DIR  256      // u32s per dir: [16 consumer][16 producer]

__device__ inline unsigned short f2bf_rne(float f){
  union { float f; unsigned int u; } v; v.f = f;
  unsigned int u = v.u;
  unsigned int r = (u + 0x7fffu + ((u >> 16) & 1u)) >> 16;
  return (unsigned short)r;
}
__device__ inline float bf2f(unsigned short s){
  union { unsigned int u; float f; } v; v.u = ((unsigned int)s) << 16;
  return v.f;
}
__device__ inline float sigm_f(float x){
  return 1.0f / (1.0f + __expf(-x));
}
__device__ inline float tanh_f(float x){
  return 1.0f - 2.0f / (__expf(2.0f * x) + 1.0f);
}

__global__ void zero_u32(unsigned* __restrict__ p, int n){
  int i = blockIdx.x * blockDim.x + threadIdx.x;
  if (i < n) p[i] = 0u;
}

// ---------------- split f32 -> bf16 hi + bf16 lo ----------------
__device__ inline void split_range(const float* __restrict__ src,
                                   ushort_t* __restrict__ hi, ushort_t* __restrict__ lo,
                                   int n4, int idx, int stride){
  for (int i = idx; i < n4; i += stride){
    f32x4 v = ((const f32x4*)src)[i];
    u16x4 h4, l4;
    #pragma unroll
    for (int j = 0; j < 4; j++){
      unsigned short h = f2bf_rne(v[j]);
      h4[j] = h;
      l4[j] = f2bf_rne(v[j] - bf2f(h));
    }
    ((u16x4*)hi)[i] = h4;
    ((u16x4*)lo)[i] = l4;
  }
}

__global__ void split_f32_bf16(const float* __restrict__ src,
                               ushort_t* __restrict__ hi, ushort_t* __restrict__ lo,
                               int n4){
  split_range(src, hi, lo, n4,
              blockIdx.x * blockDim.x + threadIdx.x, gridDim.x * blockDim.x);
}

// ---------------- split-bf16 MFMA GEMM: C = A * B^T + bias ----------------
__global__ __launch_bounds__(256) void gemm_xg(
    const ushort_t* __restrict__ Ahi, const ushort_t* __restrict__ Alo,
    const ushort_t* __restrict__ Bhi0, const ushort_t* __restrict__ Blo0,
    const ushort_t* __restrict__ Bhi1, const ushort_t* __restrict__ Blo1,
    const float* __restrict__ bi0, const float* __restrict__ bh0,
    const float* __restrict__ bi1, const float* __restrict__ bh1,
    float* __restrict__ C0, float* __restrict__ C1,
    int M, int N, int K)
{
  __shared__ ushort_t As[128*32];
  __shared__ ushort_t Bs[128*32];
  const int tid  = threadIdx.x;
  const int wave = tid >> 6, lane = tid & 63;
  const int l15 = lane & 15, l4 = lane >> 4;
  const int wr = wave >> 1, wc = wave & 1;
  const int n0 = blockIdx.x * 128, m0 = blockIdx.y * 128;
  const int dir = blockIdx.z;
  const ushort_t* Bhi = dir ? Bhi1 : Bhi0;
  const ushort_t* Blo = dir ? Blo1 : Blo0;
  const float* bia = dir ? bi1 : bi0;
  const float* bib = dir ? bh1 : bh0;
  float* C = dir ? C1 : C0;

  f32x4 acc[4][4];
  #pragma unroll
  for (int i = 0; i < 4; i++)
    #pragma unroll
    for (int j = 0; j < 4; j++) acc[i][j] = (f32x4){0.f,0.f,0.f,0.f};

  const int e0 = tid, e1 = 256 + tid;
  const int row0 = e0 >> 2, c80 = (e0 & 3) * 8;
  const int row1 = e1 >> 2, c81 = (e1 & 3) * 8;

  for (int seg = 0; seg < 3; ++seg){
    const ushort_t* Ap = (seg == 2) ? Alo : Ahi;
    const ushort_t* Bp = (seg == 1) ? Blo : Bhi;
    for (int kt = 0; kt < K; kt += 32){
      __builtin_amdgcn_global_load_lds(
        (const __attribute__((address_space(1))) unsigned int*)(Ap + (size_t)(m0 + row0) * K + kt + c80),
        (__attribute__((address_space(3))) unsigned int*)(As + e0 * 8), 16, 0, 0);
      __builtin_amdgcn_global_load_lds(
        (const __attribute__((address_space(1))) unsigned int*)(Bp + (size_t)(n0 + row0) * K + kt + c80),
        (__attribute__((address_space(3))) unsigned int*)(Bs + e0 * 8), 16, 0, 0);
      __builtin_amdgcn_global_load_lds(
        (const __attribute__((address_space(1))) unsigned int*)(Ap + (size_t)(m0 + row1) * K + kt + c81),
        (__attribute__((address_space(3))) unsigned int*)(As + e1 * 8), 16, 0, 0);
      __builtin_amdgcn_global_load_lds(
        (const __attribute__((address_space(1))) unsigned int*)(Bp + (size_t)(n0 + row1) * K + kt + c81),
        (__attribute__((address_space(3))) unsigned int*)(Bs + e1 * 8), 16, 0, 0);
      __syncthreads();
      bf16x8 af[4], bfr[4];
      #pragma unroll
      for (int m = 0; m < 4; m++)
        af[m] = *(const bf16x8*)(As + (wr*64 + m*16 + l15) * 32 + l4 * 8);
      #pragma unroll
      for (int n = 0; n < 4; n++)
        bfr[n] = *(const bf16x8*)(Bs + (wc*64 + n*16 + l15) * 32 + l4 * 8);
      #pragma unroll
      for (int m = 0; m < 4; m++)
        #pragma unroll
        for (int n = 0; n < 4; n++)
          acc[m][n] = __builtin_amdgcn_mfma_f32_16x16x32_bf16(af[m], bfr[n], acc[m][n], 0, 0, 0);
      __syncthreads();
    }
  }
  #pragma unroll
  for (int m = 0; m < 4; m++)
    #pragma unroll
    for (int n = 0; n < 4; n++){
      int col = n0 + wc*64 + n*16 + l15;
      float bias = bia[col] + bib[col];
      #pragma unroll
      for (int r = 0; r < 4; r++){
        int row = m0 + wr*64 + m*16 + l4*4 + r;
        C[(size_t)row * N + col] = acc[m][n][r] + bias;
      }
    }
}

// ---------------- persistent bidirectional LSTM layer ----------------
// Worker blocks 0..31: (dir = blk>>4, cb = blk&15), own h-cols [32*cb,+32).
// Blocks >= 32: helper blocks that perform the NEXT layer's weight splits on
// otherwise-idle CUs, then exit (no interaction with workers).
// hbuf: [dir][parity][cb][512] u32 = (bf16hi | bf16lo<<16), slot = batch*32 + col.
// Flags are REPLICATED consumer-major: flags[dir][consumer][producer]; producer
// publishes via 16 parallel lane-stores (one per consumer's private 64B line);
// each consumer polls only its own line -> 16 readers + 16 writers per line
// instead of 256 readers + 16 writers on one shared line.
// Publish safety: data stores -> __syncthreads (vmcnt drain -> visible at the
// coherence point) -> flag stores. Overwrite safety: transitive flag argument.
__global__ __launch_bounds__(512, 1) void lstm_layer(
    const float* __restrict__ whh_fwd, const float* __restrict__ whh_bwd,
    const float* __restrict__ xg,      // [2][M_][NG], m = b*T + t
    unsigned* __restrict__ hbuf,       // [2 dir][2 parity][16][512] u32
    unsigned* __restrict__ flags,      // [2 dir][16 consumer][16 producer] u32
    float* __restrict__ out_f32,       // [B][T][1024] or null
    ushort_t* __restrict__ out_hi,     // [B][T][1024] or null (split output)
    ushort_t* __restrict__ out_lo,
    const float* __restrict__ spl_src0, ushort_t* __restrict__ spl_hi0,
    ushort_t* __restrict__ spl_lo0, int spl_n0,
    const float* __restrict__ spl_src1, ushort_t* __restrict__ spl_hi1,
    ushort_t* __restrict__ spl_lo1, int spl_n1)
{
  const int tid = threadIdx.x;

  // ---- helper blocks: next-layer weight splits on idle CUs, then exit ----
  if (blockIdx.x >= 2 * NBLK_DIR){
    const int idx = (blockIdx.x - 2 * NBLK_DIR) * 512 + tid;
    const int stride = (gridDim.x - 2 * NBLK_DIR) * 512;
    if (spl_src0) split_range(spl_src0, spl_hi0, spl_lo0, spl_n0, idx, stride);
    if (spl_src1) split_range(spl_src1, spl_hi1, spl_lo1, spl_n1, idx, stride);
    return;
  }

  const int dir = blockIdx.x >> 4;
  const int cb  = blockIdx.x & 15;
  const int wave = tid >> 6, lane = tid & 63;
  const int gate = wave >> 1, ch = wave & 1;
  const int l15 = lane & 15, l4 = lane >> 4;
  const float* whh = dir ? whh_bwd : whh_fwd;
  unsigned* hb = hbuf + (size_t)dir * 2 * 8192;   // [parity][16][512] u32
  unsigned* flg = flags + (size_t)dir * FLG_DIR;  // [16 consumer][16 producer]

  __shared__ ushort_t hfhi[8192];   // fragment order: 16B unit u = colblk*16 + batch
  __shared__ ushort_t hflo[8192];
  __shared__ float gbuf[4][16][33];
  __shared__ unsigned s_token;

  // --- W_hh fragments (split bf16): wave rows gate*512 + cb*32 + ch*16 + l15 ---
  bf16x8 Whi[16], Wlo[16];
  {
    const int wrow = gate * 512 + cb * 32 + ch * 16 + l15;
    const float* p0 = whh + (size_t)wrow * 512;
    #pragma unroll
    for (int s = 0; s < 16; s++){
      const float* p = p0 + s * 32 + l4 * 8;
      f32x4 va = *(const f32x4*)(p);
      f32x4 vb = *(const f32x4*)(p + 4);
      u16x8 th, tl;
      #pragma unroll
      for (int j = 0; j < 4; j++){
        unsigned short h = f2bf_rne(va[j]);
        th[j] = h; tl[j] = f2bf_rne(va[j] - bf2f(h));
        unsigned short h2 = f2bf_rne(vb[j]);
        th[4+j] = h2; tl[4+j] = f2bf_rne(vb[j] - bf2f(h2));
      }
      Whi[s] = __builtin_bit_cast(bf16x8, th);
      Wlo[s] = __builtin_bit_cast(bf16x8, tl);
    }
  }

  const int eb = tid >> 5, ecl = tid & 31, ecol = cb * 32 + ecl;

  // consumer sweep: thread reads chunk p, batch b, 16 cols
  const int p   = tid >> 5;
  const int b5  = tid & 31;
  const int cb_b  = b5 >> 1;              // batch this thread unpacks
  const int lo1 = b5 & 1;                 // which 16-col half of the chunk row
  const int unitBase = (p * 4 + lo1 * 2) * 16 + cb_b;   // fragment unit of first colblk

  // --- init: token=0; publish own slice of h_0 (zeros); barrier-publish then flags=1 ---
  if (tid == 0) s_token = 0u;
  __hip_atomic_store(&hb[cb * 512 + tid], 0u, __ATOMIC_RELAXED, __HIP_MEMORY_SCOPE_AGENT);
  __syncthreads();   // drains vmcnt: stores visible at coherence point; token init visible
  if (tid < NBLK_DIR)
    __hip_atomic_store(&flg[tid * NBLK_DIR + cb], 1u, __ATOMIC_RELAXED, __HIP_MEMORY_SCOPE_AGENT);

  float c_state = 0.0f;

  for (int t = 0; t < T_; ++t){
    // A) prefetch xg for this step (first drain is the post-sweep barrier)
    const int t_eff = dir ? (T_ - 1 - t) : t;
    const float* xgp = xg + ((size_t)dir * M_ + (size_t)eb * T_ + t_eff) * NG + ecol;
    float xi = xgp[0];
    float xf = xgp[512];
    float xgg = xgp[1024];
    float xo = xgp[1536];

    // B) release: wave 0 polls THIS consumer's private flag line; LDS token frees waves 1-7
    const unsigned want = (unsigned)(t + 1);
    if (wave == 0){
      if (lane < NBLK_DIR){
        const unsigned* f = &flg[cb * NBLK_DIR + lane];
        while (__hip_atomic_load(f, __ATOMIC_RELAXED, __HIP_MEMORY_SCOPE_AGENT) < want)
          __builtin_amdgcn_s_sleep(1);
      }
      if (lane == 0)
        __hip_atomic_store(&s_token, want, __ATOMIC_RELEASE, __HIP_MEMORY_SCOPE_WORKGROUP);
    } else {
      while (__hip_atomic_load(&s_token, __ATOMIC_ACQUIRE, __HIP_MEMORY_SCOPE_WORKGROUP) < want)
        __builtin_amdgcn_s_sleep(1);
    }

    // C) per-wave bulk sweep: 8 contiguous u64 (64B/thread; wave = 4KB linear)
    const u64* src = (const u64*)(hb + (size_t)(t & 1) * 8192) + (size_t)p * 256 + (size_t)b5 * 8;
    u64 v[8];
    #pragma unroll
    for (int k = 0; k < 8; k++)
      v[k] = __hip_atomic_load(&src[k], __ATOMIC_RELAXED, __HIP_MEMORY_SCOPE_AGENT);

    // unpack into fragment LDS: 2 units (b128) per array
    {
      u32x4 wh0, wh1, wl0, wl1;
      #pragma unroll
      for (int k = 0; k < 4; k++){
        unsigned d0 = (unsigned)v[k], d1 = (unsigned)(v[k] >> 32);
        wh0[k] = (d0 & 0xffffu) | (d1 << 16);
        wl0[k] = (d0 >> 16) | (d1 & 0xffff0000u);
      }
      #pragma unroll
      for (int k = 0; k < 4; k++){
        unsigned d0 = (unsigned)v[4 + k], d1 = (unsigned)(v[4 + k] >> 32);
        wh1[k] = (d0 & 0xffffu) | (d1 << 16);
        wl1[k] = (d0 >> 16) | (d1 & 0xffff0000u);
      }
      ((u32x4*)hfhi)[unitBase]      = wh0;
      ((u32x4*)hfhi)[unitBase + 16] = wh1;
      ((u32x4*)hflo)[unitBase]      = wl0;
      ((u32x4*)hflo)[unitBase + 16] = wl1;
    }
    __syncthreads();   // barrier #2: LDS consistency; drains sweep + (hidden) xg loads

    // D) gates: 3 independent MFMA chains
    {
      f32x4 a0 = {0.f,0.f,0.f,0.f}, a1 = a0, a2 = a0;
      #pragma unroll
      for (int s = 0; s < 16; s++){
        bf16x8 ah = *(const bf16x8*)&hfhi[(s * 64 + l4 * 16 + l15) * 8];
        bf16x8 al = *(const bf16x8*)&hflo[(s * 64 + l4 * 16 + l15) * 8];
        a0 = __builtin_amdgcn_mfma_f32_16x16x32_bf16(ah, Whi[s], a0, 0, 0, 0);
        a1 = __builtin_amdgcn_mfma_f32_16x16x32_bf16(ah, Wlo[s], a1, 0, 0, 0);
        a2 = __builtin_amdgcn_mfma_f32_16x16x32_bf16(al, Whi[s], a2, 0, 0, 0);
      }
      f32x4 acc = a0 + a1;
      acc = acc + a2;
      #pragma unroll
      for (int r = 0; r < 4; r++)
        gbuf[gate][l4 * 4 + r][ch * 16 + l15] = acc[r];
    }
    __syncthreads();   // barrier #3: gbuf cross-wave

    // E) cell; data store -> barrier-publish -> replicated flag stores; out stores last
    float h; unsigned short hh, hl; size_t oidx;
    {
      float pi = gbuf[0][eb][ecl] + xi;
      float pf = gbuf[1][eb][ecl] + xf;
      float pg = gbuf[2][eb][ecl] + xgg;
      float po = gbuf[3][eb][ecl] + xo;
      float ig = sigm_f(pi);
      float fg = sigm_f(pf);
      float gg = tanh_f(pg);
      float og = sigm_f(po);
      c_state = fg * c_state + ig * gg;
      h = og * tanh_f(c_state);
      hh = f2bf_rne(h);
      hl = f2bf_rne(h - bf2f(hh));
      oidx = ((size_t)eb * T_ + t_eff) * 1024 + dir * 512 + ecol;
      __hip_atomic_store(&hb[(size_t)((t + 1) & 1) * 8192 + cb * 512 + tid],
                         (unsigned)hh | ((unsigned)hl << 16),
                         __ATOMIC_RELAXED, __HIP_MEMORY_SCOPE_AGENT);
    }
    __syncthreads();   // barrier #4: drains vmcnt -> h stores visible before flags
    if (tid < NBLK_DIR)
      __hip_atomic_store(&flg[tid * NBLK_DIR + cb], (unsigned)(t + 2),
                         __ATOMIC_RELAXED, __HIP_MEMORY_SCOPE_AGENT);
    if (out_f32) out_f32[oidx] = h;
    if (out_hi){ out_hi[oidx] = hh; out_lo[oidx] = hl; }
  }
}

// ---------------- attention pooling ----------------
__device__ inline float dot4(f32x4 a, f32x4 b){
  return a[0]*b[0] + a[1]*b[1] + a[2]*b[2] + a[3]*b[3];
}

__global__ __launch_bounds__(256) void attn_pool(
    const float* __restrict__ out1,   // [B][T][1024]
    const float* __restrict__ aw,     // [1024]
    const float* __restrict__ ab,     // [1]
    float* __restrict__ enc)          // [B][1024]
{
  __shared__ float wbuf[1024];
  __shared__ float sc[1024];
  __shared__ float red[16];
  const int b = blockIdx.x;
  const int tid = threadIdx.x;
  const int wave = tid >> 6, lane = tid & 63;
  ((f32x4*)wbuf)[tid] = ((const f32x4*)aw)[tid];
  __syncthreads();
  const float* ob = out1 + (size_t)b * T_ * 1024;
  const float bias = ab[0];

  for (int t = wave; t < T_; t += 4){
    const float* row = ob + (size_t)t * 1024;
    float s = dot4(((const f32x4*)row)[lane],       ((const f32x4*)wbuf)[lane])
            + dot4(((const f32x4*)row)[lane + 64],  ((const f32x4*)wbuf)[lane + 64])
            + dot4(((const f32x4*)row)[lane + 128], ((const f32x4*)wbuf)[lane + 128])
            + dot4(((const f32x4*)row)[lane + 192], ((const f32x4*)wbuf)[lane + 192]);
    #pragma unroll
    for (int o = 32; o > 0; o >>= 1) s += __shfl_xor(s, o, 64);
    if (lane == 0) sc[t] = s + bias;
  }
  __syncthreads();

  float m = -1e30f;
  for (int i = tid; i < 1024; i += 256) m = fmaxf(m, sc[i]);
  #pragma unroll
  for (int o = 32; o > 0; o >>= 1) m = fmaxf(m, __shfl_xor(m, o, 64));
  if (lane == 0) red[wave] = m;
  __syncthreads();
  m = fmaxf(fmaxf(red[0], red[1]), fmaxf(red[2], red[3]));

  float ssum = 0.f;
  for (int i = tid; i < 1024; i += 256){
    float p = __expf(sc[i] - m);
    sc[i] = p;
    ssum += p;
  }
  #pragma unroll
  for (int o = 32; o > 0; o >>= 1) ssum += __shfl_xor(ssum, o, 64);
  if (lane == 0) red[8 + wave] = ssum;
  __syncthreads();
  float inv = 1.0f / (red[8] + red[9] + red[10] + red[11]);

  f32x4 a = {0.f,0.f,0.f,0.f};
  for (int t = 0; t < T_; t++){
    f32x4 v = *(const f32x4*)(ob + (size_t)t * 1024 + tid * 4);
    float p = sc[t];
    a[0] += p * v[0]; a[1] += p * v[1]; a[2] += p * v[2]; a[3] += p * v[3];
  }
  f32x4 r = { a[0]*inv, a[1]*inv, a[2]*inv, a[3]*inv };
  *(f32x4*)(enc + (size_t)b * 1024 + tid * 4) = r;
}

// ---------------- host ----------------
extern "C" void kernel_launch(void* const* d_in, const int* in_sizes, int n_in,
                              void* d_out, int out_size, void* d_ws, size_t ws_size,
                              hipStream_t stream)
{
  const float* x        = (const float*)d_in[0];
  const float* w_ih_l0  = (const float*)d_in[1];
  const float* w_hh_l0  = (const float*)d_in[2];
  const float* b_ih_l0  = (const float*)d_in[3];
  const float* b_hh_l0  = (const float*)d_in[4];
  const float* w_ih_l0r = (const float*)d_in[5];
  const float* w_hh_l0r = (const float*)d_in[6];
  const float* b_ih_l0r = (const float*)d_in[7];
  const float* b_hh_l0r = (const float*)d_in[8];
  const float* w_ih_l1  = (const float*)d_in[9];
  const float* w_hh_l1  = (const float*)d_in[10];
  const float* b_ih_l1  = (const float*)d_in[11];
  const float* b_hh_l1  = (const float*)d_in[12];
  const float* w_ih_l1r = (const float*)d_in[13];
  const float* w_hh_l1r = (const float*)d_in[14];
  const float* b_ih_l1r = (const float*)d_in[15];
  const float* b_hh_l1r = (const float*)d_in[16];
  const float* attn_w   = (const float*)d_in[17];
  const float* attn_b   = (const float*)d_in[18];
  float* enc = (float*)d_out;

  char* ws = (char*)d_ws;
  size_t off = 0;
  auto alloc = [&](size_t bytes) -> void* {
    void* p = ws + off;
    off += (bytes + 255) & ~(size_t)255;
    return p;
  };
  ushort_t* Ahi  = (ushort_t*)alloc((size_t)M_ * 2048 * 2);
  ushort_t* Alo  = (ushort_t*)alloc((size_t)M_ * 2048 * 2);
  ushort_t* Whi0 = (ushort_t*)alloc((size_t)2048 * 2048 * 2);
  ushort_t* Wlo0 = (ushort_t*)alloc((size_t)2048 * 2048 * 2);
  ushort_t* Whi1 = (ushort_t*)alloc((size_t)2048 * 2048 * 2);
  ushort_t* Wlo1 = (ushort_t*)alloc((size_t)2048 * 2048 * 2);
  float*    xg   = (float*)alloc((size_t)2 * M_ * NG * 4);
  float*    outb = (float*)alloc((size_t)M_ * 1024 * 4);
  unsigned* hbuf = (unsigned*)alloc((size_t)2 * 2 * 2 * 8192 * 4);  // [layer][dir][parity][16][512] u32
  unsigned* flags= (unsigned*)alloc((size_t)2 * 2 * FLG_DIR * 4);   // [layer][dir][cons][prod]
  if (off > ws_size){
    fprintf(stderr, "kernel_launch: workspace too small: need %zu have %zu\n", off, ws_size);
    return;
  }

  // zero h buffers + flags every call (replay-deterministic; contiguous in ws)
  {
    int n = 2 * 2 * 2 * 8192 + 2 * 2 * FLG_DIR;
    zero_u32<<<(n + 255) / 256, 256, 0, stream>>>(hbuf, n);
  }

  // ---- layer 0 ----
  split_f32_bf16<<<2048, 256, 0, stream>>>(x, Ahi, Alo, M_ * 2048 / 4);
  split_f32_bf16<<<512, 256, 0, stream>>>(w_ih_l0,  Whi0, Wlo0, 2048 * 2048 / 4);
  split_f32_bf16<<<512, 256, 0, stream>>>(w_ih_l0r, Whi1, Wlo1, 2048 * 2048 / 4);
  gemm_xg<<<dim3(16, 128, 2), 256, 0, stream>>>(
      Ahi, Alo, Whi0, Wlo0, Whi1, Wlo1,
      b_ih_l0, b_hh_l0, b_ih_l0r, b_hh_l0r,
      xg, xg + (size_t)M_ * NG, M_, NG, 2048);
  // LSTM layer 0 (32 worker blocks) + layer-1 weight splits on 224 helper blocks
  lstm_layer<<<256, 512, 0, stream>>>(w_hh_l0, w_hh_l0r, xg, hbuf, flags,
                                      nullptr, Ahi, Alo,
                                      w_ih_l1,  Whi0, Wlo0, 2048 * 1024 / 4,
                                      w_ih_l1r, Whi1, Wlo1, 2048 * 1024 / 4);
  // ---- layer 1 ----
  gemm_xg<<<dim3(16, 128, 2), 256, 0, stream>>>(
      Ahi, Alo, Whi0, Wlo0, Whi1, Wlo1,
      b_ih_l1, b_hh_l1, b_ih_l1r, b_hh_l1r,
      xg, xg + (size_t)M_ * NG, M_, NG, 1024);
  lstm_layer<<<32, 512, 0, stream>>>(w_hh_l1, w_hh_l1r, xg,
                                     hbuf + (size_t)2 * 2 * 8192,
                                     flags + (size_t)2 * FLG_DIR,
                                     outb, nullptr, nullptr,
                                     nullptr, nullptr, nullptr, 0,
                                     nullptr, nullptr, nullptr, 0);
  // ---- attention pooling ----
  attn_pool<<<16, 256, 0, stream>>>(outb, attn_w, attn_b, enc);
}